// Round 10
// baseline (485.968 us; speedup 1.0000x reference)
//
#include <hip/hip_runtime.h>
#include <cstddef>
#include <cstdint>

typedef short  bf16x8 __attribute__((ext_vector_type(8)));
typedef float  f32x16 __attribute__((ext_vector_type(16)));

#define IC 2048
#define JD 16
#define NC 64
#define DD 32
#define ICH 16
#define NPG (IC / ICH)         // 128 sPart pages

// ---------------------------------------------------------------- helpers ---
__device__ __forceinline__ unsigned f2bf1(float f) {          // RNE f32->bf16
  unsigned u = __float_as_uint(f);
  return (u + 0x7FFFu + ((u >> 16) & 1u)) >> 16;
}
__device__ __forceinline__ unsigned pk2(float lo, float hi) { // 2 bf16 in u32
  return f2bf1(lo) | (f2bf1(hi) << 16);
}
__device__ __forceinline__ float bflo(unsigned v) { return __uint_as_float(v << 16); }
__device__ __forceinline__ float bfhi(unsigned v) { return __uint_as_float(v & 0xFFFF0000u); }

template<int CTRL>
__device__ __forceinline__ float dpp_mov_f(float v) {
  int x = __builtin_amdgcn_mov_dpp(__float_as_int(v), CTRL, 0xf, 0xf, true);
  return __int_as_float(x);
}
__device__ __forceinline__ float row16_sum(float v) {
  v += dpp_mov_f<0x121>(v);
  v += dpp_mov_f<0x122>(v);
  v += dpp_mov_f<0x124>(v);
  v += dpp_mov_f<0x128>(v);
  return v;
}

// async global->LDS, 16B per lane. LDS dest = wave-uniform base + lane*16;
// global src is PER-LANE (pre-swizzled to fragment order).
__device__ __forceinline__ void gload16(const void* g, void* l) {
  __builtin_amdgcn_global_load_lds(
      (const __attribute__((address_space(1))) unsigned int*)g,
      (__attribute__((address_space(3))) unsigned int*)l, 16, 0, 0);
}
#define WAITV(N) asm volatile("s_waitcnt vmcnt(" #N ")" ::: "memory")
#define WAITL    asm volatile("s_waitcnt lgkmcnt(0)" ::: "memory")

// ========================================================= MFMA path ========
// Wb layout (LINEAR FRAGMENT ORDER): row(n,i) = 512 ushort; granule l (16B)
// = W[n][i][d=l&31][j=(l>>5)*8 .. +8] as bf16. Producers store at row+l*16,
// consumers gload with per-lane src row+l*16 and ds_read at lds+l*16.

// accum r0 (+ W f32->bf16 conversion; each element owned by exactly 1 wave).
// grid 1024 = 128 ic x 8 nq; 256 thr; wave w owns n0=nq*8+w*2, n0+1.
__global__ __launch_bounds__(256, 4) void caps_accum0(
    const float* __restrict__ x, const float* __restrict__ Wf,
    unsigned short* __restrict__ Wb, float* __restrict__ sPart)
{
  const int t = threadIdx.x, w = t >> 6, l = t & 63;
  const int m = l & 31, h = l >> 5;
  const int ic = blockIdx.x >> 3, nq = blockIdx.x & 7;
  const int i0 = ic * ICH;
  const int n0 = nq * 8 + w * 2;
  __shared__ __align__(16) unsigned short xlg[ICH][512];   // 16 KB, frag order
  __shared__ __align__(16) float wstF[4][2][2][512];       // 32 KB: w,slot,row

  for (int gg = t; gg < ICH * 64; gg += 256) {             // x -> bf16 frags
    int il = gg >> 6, ll = gg & 63;
    const float* xs = x + ((size_t)(ll & 31) * IC + (i0 + il)) * JD + (ll >> 5) * 8;
    float4 xa = *reinterpret_cast<const float4*>(xs);
    float4 xb = *reinterpret_cast<const float4*>(xs + 4);
    uint4 pv;
    pv.x = pk2(xa.x, xa.y); pv.y = pk2(xa.z, xa.w);
    pv.z = pk2(xb.x, xb.y); pv.w = pk2(xb.z, xb.w);
    *reinterpret_cast<uint4*>(&xlg[il][ll * 8]) = pv;
  }
  __syncthreads();

  const int gOffA = m * 16 + h * 8;   // f32 els: fragment-order src offset
#define A0_STAGE(il) { \
    size_t r0 = ((size_t)n0 * IC + (i0 + (il))) * 512 + gOffA; \
    size_t r1 = r0 + (size_t)IC * 512; \
    gload16(Wf + r0,     &wstF[w][(il) & 1][0][0]); \
    gload16(Wf + r0 + 4, &wstF[w][(il) & 1][0][256]); \
    gload16(Wf + r1,     &wstF[w][(il) & 1][1][0]); \
    gload16(Wf + r1 + 4, &wstF[w][(il) & 1][1][256]); }

  A0_STAGE(0)
  A0_STAGE(1)
  f32x16 sacc0 = (f32x16)0.0f, sacc1 = (f32x16)0.0f;
#pragma unroll
  for (int il = 0; il < ICH; ++il) {
    if (il == 0)       { WAITV(4); }     // prologue S1 younger
    else if (il == 15) { WAITV(2); }     // only st14 younger
    else               { WAITV(6); }     // st(il-1)+S(il+1)
    const int sl = il & 1;
    float4 a0 = *reinterpret_cast<const float4*>(&wstF[w][sl][0][(size_t)l * 4]);
    float4 a1 = *reinterpret_cast<const float4*>(&wstF[w][sl][0][256 + (size_t)l * 4]);
    float4 b0 = *reinterpret_cast<const float4*>(&wstF[w][sl][1][(size_t)l * 4]);
    float4 b1 = *reinterpret_cast<const float4*>(&wstF[w][sl][1][256 + (size_t)l * 4]);
    uint4 pA, pB;
    pA.x = pk2(a0.x, a0.y); pA.y = pk2(a0.z, a0.w);
    pA.z = pk2(a1.x, a1.y); pA.w = pk2(a1.z, a1.w);
    pB.x = pk2(b0.x, b0.y); pB.y = pk2(b0.z, b0.w);
    pB.z = pk2(b1.x, b1.y); pB.w = pk2(b1.z, b1.w);
    bf16x8 bfrag = *reinterpret_cast<const bf16x8*>(&xlg[il][(size_t)l * 8]);
    sacc0 = __builtin_amdgcn_mfma_f32_32x32x16_bf16(
        *reinterpret_cast<bf16x8*>(&pA), bfrag, sacc0, 0, 0, 0);
    sacc1 = __builtin_amdgcn_mfma_f32_32x32x16_bf16(
        *reinterpret_cast<bf16x8*>(&pB), bfrag, sacc1, 0, 0, 0);
    *reinterpret_cast<uint4*>(Wb + ((size_t)n0 * IC + (i0 + il)) * 512 + (size_t)l * 8) = pA;
    *reinterpret_cast<uint4*>(Wb + ((size_t)(n0 + 1) * IC + (i0 + il)) * 512 + (size_t)l * 8) = pB;
    WAITL;                               // ds_reads retired before slot reuse
    if (il + 2 < ICH) A0_STAGE(il + 2)
  }
#undef A0_STAGE
  float* page = sPart + (size_t)ic * 65536;      // [n][d/4][b][4]
#pragma unroll
  for (int q = 0; q < 4; ++q) {
    float4 v0 = make_float4(sacc0[4*q]*0.015625f, sacc0[4*q+1]*0.015625f,
                            sacc0[4*q+2]*0.015625f, sacc0[4*q+3]*0.015625f);
    float4 v1 = make_float4(sacc1[4*q]*0.015625f, sacc1[4*q+1]*0.015625f,
                            sacc1[4*q+2]*0.015625f, sacc1[4*q+3]*0.015625f);
    *reinterpret_cast<float4*>(page + (((size_t)n0*8 + 2*q+h)*32 + m)*4) = v0;
    *reinterpret_cast<float4*>(page + ((((size_t)n0+1)*8 + 2*q+h)*32 + m)*4) = v1;
  }
}

// logits (r>=1): grid 2048 (one i); 4 waves x 16 nn. Writes C[i][n][b]=e/den.
__global__ __launch_bounds__(256, 8) void caps_logits(
    const float* __restrict__ x, const unsigned short* __restrict__ Wb,
    const unsigned short* __restrict__ Vb, float* __restrict__ C)
{
  const int t = threadIdx.x, w = t >> 6, l = t & 63;
  const int m = l & 31, h = l >> 5;
  const int i = blockIdx.x;
  __shared__ __align__(16) unsigned short xlg[512];        // 1 KB
  __shared__ __align__(16) unsigned short wstL[4][2][512]; // 8 KB
  __shared__ float den4[4][32];
  __shared__ float denf[32];
  if (t < 64) {
    const float* xs = x + ((size_t)(t & 31) * IC + i) * JD + (t >> 5) * 8;
    float4 xa = *reinterpret_cast<const float4*>(xs);
    float4 xb = *reinterpret_cast<const float4*>(xs + 4);
    uint4 pv;
    pv.x = pk2(xa.x, xa.y); pv.y = pk2(xa.z, xa.w);
    pv.z = pk2(xb.x, xb.y); pv.w = pk2(xb.z, xb.w);
    *reinterpret_cast<uint4*>(&xlg[t * 8]) = pv;
  }
  __syncthreads();
  bf16x8 bfrag = *reinterpret_cast<const bf16x8*>(&xlg[(size_t)l * 8]);
#define L_STAGE(nn) gload16( \
    Wb + ((size_t)(w * 16 + (nn)) * IC + i) * 512 + (size_t)l * 8, \
    &wstL[w][(nn) & 1][0]);
  L_STAGE(0)
  L_STAGE(1)
  float e[16];
  float pden = 0.f;
#pragma unroll
  for (int nn = 0; nn < 16; ++nn) {
    if (nn == 0)       { WAITV(1); }
    else if (nn == 15) { WAITV(4); }
    else               { WAITV(5); }     // V(nn-1) x4 + S(nn+1)
    bf16x8 af = *reinterpret_cast<const bf16x8*>(&wstL[w][nn & 1][(size_t)l * 8]);
    const int n = w * 16 + nn;
    f32x16 u = __builtin_amdgcn_mfma_f32_32x32x16_bf16(
        af, bfrag, (f32x16)0.0f, 0, 0, 0);
    float partial = 0.f;
    const unsigned short* vrow = Vb + ((size_t)m * NC + n) * DD;
#pragma unroll
    for (int q = 0; q < 4; ++q) {                // 4 global V loads (counted)
      uint2 vv = *reinterpret_cast<const uint2*>(vrow + (2 * q + h) * 4);
      partial += bflo(vv.x) * u[4*q+0] + bfhi(vv.x) * u[4*q+1]
               + bflo(vv.y) * u[4*q+2] + bfhi(vv.y) * u[4*q+3];
    }
    float logit = partial + __shfl_xor(partial, 32);
    e[nn] = __expf(logit);   // |logit| small (V squashed); shift-invariant
    pden += e[nn];
    WAITL;
    if (nn + 2 < 16) L_STAGE(nn + 2)
  }
#undef L_STAGE
  if (h == 0) den4[w][m] = pden;
  __syncthreads();
  if (t < 32) denf[t] = 1.0f / (den4[0][t] + den4[1][t] + den4[2][t] + den4[3][t]);
  __syncthreads();
  if (h == 0) {
    float rden = denf[m];
    float* crow = C + ((size_t)i * NC + w * 16) * 32 + m;
#pragma unroll
    for (int nn = 0; nn < 16; ++nn) crow[nn * 32] = e[nn] * rden;
  }
}

// accum r1/r2: weighted GEMM. x + C pre-staged in LDS; Wb via async stage.
__global__ __launch_bounds__(256, 4) void caps_accum12(
    const float* __restrict__ x, const unsigned short* __restrict__ Wb,
    const float* __restrict__ C, float* __restrict__ sPart)
{
  const int t = threadIdx.x, w = t >> 6, l = t & 63;
  const int m = l & 31, h = l >> 5;
  const int ic = blockIdx.x >> 3, nq = blockIdx.x & 7;
  const int i0 = ic * ICH;
  const int n0 = nq * 8 + w * 2;
  __shared__ __align__(16) unsigned short xlg[ICH][512];     // 16 KB
  __shared__ __align__(16) unsigned short wstB[4][2][2][512];// 8 KB
  __shared__ float Cl[ICH][8][32];                           // 16 KB

  for (int gg = t; gg < ICH * 64; gg += 256) {
    int il = gg >> 6, ll = gg & 63;
    const float* xs = x + ((size_t)(ll & 31) * IC + (i0 + il)) * JD + (ll >> 5) * 8;
    float4 xa = *reinterpret_cast<const float4*>(xs);
    float4 xb = *reinterpret_cast<const float4*>(xs + 4);
    uint4 pv;
    pv.x = pk2(xa.x, xa.y); pv.y = pk2(xa.z, xa.w);
    pv.z = pk2(xb.x, xb.y); pv.w = pk2(xb.z, xb.w);
    *reinterpret_cast<uint4*>(&xlg[il][ll * 8]) = pv;
  }
  for (int fid = t; fid < ICH * 64; fid += 256) {            // C slice 16 KB
    int il = fid >> 6, nn2 = (fid >> 3) & 7, mq = fid & 7;
    *reinterpret_cast<float4*>(&Cl[il][nn2][mq * 4]) =
        *reinterpret_cast<const float4*>(
            C + (((size_t)(i0 + il)) * NC + nq * 8 + nn2) * 32 + mq * 4);
  }
  __syncthreads();

#define B_STAGE(il) { \
    size_t r0 = ((size_t)n0 * IC + (i0 + (il))) * 512 + (size_t)l * 8; \
    gload16(Wb + r0,                    &wstB[w][(il) & 1][0][0]); \
    gload16(Wb + r0 + (size_t)IC * 512, &wstB[w][(il) & 1][1][0]); }
  B_STAGE(0)
  B_STAGE(1)
  f32x16 sacc0 = (f32x16)0.0f, sacc1 = (f32x16)0.0f;
#pragma unroll
  for (int il = 0; il < ICH; ++il) {
    if (il == 15) { WAITV(0); } else { WAITV(2); }
    const int sl = il & 1;
    bf16x8 af0 = *reinterpret_cast<const bf16x8*>(&wstB[w][sl][0][(size_t)l * 8]);
    bf16x8 af1 = *reinterpret_cast<const bf16x8*>(&wstB[w][sl][1][(size_t)l * 8]);
    bf16x8 bfrag = *reinterpret_cast<const bf16x8*>(&xlg[il][(size_t)l * 8]);
    float c0 = Cl[il][w * 2][m];
    float c1 = Cl[il][w * 2 + 1][m];
    f32x16 u0 = __builtin_amdgcn_mfma_f32_32x32x16_bf16(
        af0, bfrag, (f32x16)0.0f, 0, 0, 0);
    f32x16 u1 = __builtin_amdgcn_mfma_f32_32x32x16_bf16(
        af1, bfrag, (f32x16)0.0f, 0, 0, 0);
#pragma unroll
    for (int k = 0; k < 16; ++k) {
      sacc0[k] += c0 * u0[k];
      sacc1[k] += c1 * u1[k];
    }
    WAITL;
    if (il + 2 < ICH) B_STAGE(il + 2)
  }
#undef B_STAGE
  float* page = sPart + (size_t)ic * 65536;
#pragma unroll
  for (int q = 0; q < 4; ++q) {
    float4 v0 = make_float4(sacc0[4*q], sacc0[4*q+1], sacc0[4*q+2], sacc0[4*q+3]);
    float4 v1 = make_float4(sacc1[4*q], sacc1[4*q+1], sacc1[4*q+2], sacc1[4*q+3]);
    *reinterpret_cast<float4*>(page + (((size_t)n0*8 + 2*q+h)*32 + m)*4) = v0;
    *reinterpret_cast<float4*>(page + ((((size_t)n0+1)*8 + 2*q+h)*32 + m)*4) = v1;
  }
}

// reduce level 1: 128 pages -> 8 partial pages
__global__ __launch_bounds__(256) void caps_reduce1(
    const float4* __restrict__ sPart, float4* __restrict__ part2) {
  int blk = blockIdx.x;              // 512 = 8 pg x 64 fb
  int pg = blk >> 6, fb = blk & 63;
  int fid = fb * 256 + threadIdx.x;  // 0..16383
  float4 a = make_float4(0.f, 0.f, 0.f, 0.f);
#pragma unroll 8
  for (int p = 0; p < 16; ++p) {
    float4 v = sPart[(size_t)(pg * 16 + p) * 16384 + fid];
    a.x += v.x; a.y += v.y; a.z += v.z; a.w += v.w;
  }
  part2[(size_t)pg * 16384 + fid] = a;
}

// fused reduce level 2 + squash; emits V (f32) and Vb (bf16).
__global__ __launch_bounds__(256) void caps_redsq(
    const float4* __restrict__ part2, float* __restrict__ V,
    unsigned short* __restrict__ Vb, float* __restrict__ out, int mode)
{
  const int n = blockIdx.x, t = threadIdx.x;
  const int dc = t >> 5, b = t & 31;
  const int fid = n * 256 + t;
  __shared__ float sq[8][32];
  float4 a = make_float4(0.f, 0.f, 0.f, 0.f);
#pragma unroll
  for (int pg = 0; pg < 8; ++pg) {
    float4 v = part2[(size_t)pg * 16384 + fid];
    a.x += v.x; a.y += v.y; a.z += v.z; a.w += v.w;
  }
  sq[dc][b] = a.x*a.x + a.y*a.y + a.z*a.z + a.w*a.w;
  __syncthreads();
  float s2 = 0.f;
#pragma unroll
  for (int q = 0; q < 8; ++q) s2 += sq[q][b];
  float scale = s2 / ((1.0f + s2) * sqrtf(s2 + 1e-7f));
  float4 vd = make_float4(a.x*scale, a.y*scale, a.z*scale, a.w*scale);
  const size_t off = ((size_t)b * NC + n) * DD + dc * 4;
  if (mode == 2) {
    *reinterpret_cast<float4*>(out + off) = vd;
  } else {
    float4 nv = vd;
    if (mode == 1) {
      float4 old = *reinterpret_cast<const float4*>(V + off);
      nv.x += old.x; nv.y += old.y; nv.z += old.z; nv.w += old.w;
    }
    *reinterpret_cast<float4*>(V + off) = nv;
    uint2 pb;
    pb.x = pk2(nv.x, nv.y);
    pb.y = pk2(nv.z, nv.w);
    *reinterpret_cast<uint2*>(Vb + off) = pb;
  }
}

// ============================== fallback: R6 f32 path (ws too small) ========
__global__ void fb_zero(float* __restrict__ s) {
  s[blockIdx.x * 256 + threadIdx.x] = 0.0f;
}
__global__ __launch_bounds__(1024, 4)
void fb_pass(const float* __restrict__ x, const float* __restrict__ W,
             const float* __restrict__ V, float* __restrict__ sOut,
             float* __restrict__ sPart, int r, int usePart)
{
  const int t = threadIdx.x, w = t >> 6, l = t & 63;
  const int n = (w << 2) | (l >> 4);
  const int d0 = (l & 15) << 1;
  const int blk = blockIdx.x, xcd = blk & 7, slot = blk >> 3;
  const int ic = xcd * 8 + (slot >> 3), bq = slot & 7;
  const int i0 = ic * 32, bbase = bq * 4;
  __shared__ float den[2][4];
  __shared__ float Vlds[4 * NC * DD];
  if (r != 0) {
    const float4* src = reinterpret_cast<const float4*>(V + (size_t)bbase * 2048);
    float4* dst = reinterpret_cast<float4*>(Vlds);
    dst[t] = src[t]; dst[t + 1024] = src[t + 1024];
  }
  float acc0[4], acc1[4];
#pragma unroll
  for (int b = 0; b < 4; ++b) { acc0[b] = 0.f; acc1[b] = 0.f; }
  for (int ii = 0; ii < 32; ++ii) {
    const int i = i0 + ii, p = ii & 1;
    const float4* Wp = reinterpret_cast<const float4*>(
        W + (((size_t)n * IC + i) * DD + d0) * JD);
    float4 wr[8];
#pragma unroll
    for (int q = 0; q < 8; ++q) wr[q] = Wp[q];
    if (r == 0) {
#pragma unroll
      for (int bb = 0; bb < 4; ++bb) {
        const float* xp = x + ((size_t)(bbase + bb) * IC + i) * JD;
        float u0 = 0.f, u1 = 0.f;
#pragma unroll
        for (int q = 0; q < 4; ++q) {
          float4 w0 = wr[q], w1 = wr[4 + q];
          float x0 = xp[4*q], x1 = xp[4*q+1], x2 = xp[4*q+2], x3 = xp[4*q+3];
          u0 += w0.x*x0 + w0.y*x1 + w0.z*x2 + w0.w*x3;
          u1 += w1.x*x0 + w1.y*x1 + w1.z*x2 + w1.w*x3;
        }
        acc0[bb] += u0 * 0.015625f; acc1[bb] += u1 * 0.015625f;
      }
    } else {
      if (t < 4) den[p][t] = 0.0f;
      __syncthreads();
      float p0a[4], p1a[4];
#pragma unroll
      for (int bb = 0; bb < 4; ++bb) {
        const float* xp = x + ((size_t)(bbase + bb) * IC + i) * JD;
        float u0 = 0.f, u1 = 0.f;
#pragma unroll
        for (int q = 0; q < 4; ++q) {
          float4 w0 = wr[q], w1 = wr[4 + q];
          float x0 = xp[4*q], x1 = xp[4*q+1], x2 = xp[4*q+2], x3 = xp[4*q+3];
          u0 += w0.x*x0 + w0.y*x1 + w0.z*x2 + w0.w*x3;
          u1 += w1.x*x0 + w1.y*x1 + w1.z*x2 + w1.w*x3;
        }
        const float2 vv = *reinterpret_cast<const float2*>(
            &Vlds[((size_t)bb * NC + n) * DD + d0]);
        float lp = u0 * vv.x + u1 * vv.y;
        float logit = row16_sum(lp);
        float e = __expf(logit);
        p0a[bb] = e * u0; p1a[bb] = e * u1;
        float es = e + __shfl_xor(e, 16);
        es += __shfl_xor(es, 32);
        if (l == 0) atomicAdd(&den[p][bb], es);
      }
      __syncthreads();
#pragma unroll
      for (int bb = 0; bb < 4; ++bb) {
        float rd = 1.0f / den[p][bb];
        acc0[bb] += p0a[bb] * rd; acc1[bb] += p1a[bb] * rd;
      }
    }
  }
  if (usePart) {
#pragma unroll
    for (int bb = 0; bb < 4; ++bb) {
      float2 v2 = make_float2(acc0[bb], acc1[bb]);
      size_t off = (((size_t)(bq * 64 + ic) * 4 + bb) * NC + n) * DD + d0;
      *reinterpret_cast<float2*>(sPart + off) = v2;
    }
  } else {
#pragma unroll
    for (int bb = 0; bb < 4; ++bb) {
      float* sp = sOut + ((size_t)(bbase + bb) * NC + n) * DD + d0;
      atomicAdd(sp, acc0[bb]); atomicAdd(sp + 1, acc1[bb]);
    }
  }
}
__global__ void fb_reduceS(const float4* __restrict__ sPart, float4* __restrict__ s) {
  int q = blockIdx.x * 256 + threadIdx.x;
  int bq = q >> 11, qq = q & 2047;
  float4 sum = make_float4(0.f, 0.f, 0.f, 0.f);
#pragma unroll 8
  for (int p = 0; p < 64; ++p) {
    float4 v = sPart[(size_t)(bq * 64 + p) * 2048 + qq];
    sum.x += v.x; sum.y += v.y; sum.z += v.z; sum.w += v.w;
  }
  s[q] = sum;
}
__global__ void fb_squash(const float* __restrict__ s, float* __restrict__ V,
                          float* __restrict__ out, int mode)
{
  const int t = threadIdx.x;
  const int g = blockIdx.x * 8 + (t >> 5);
  const int d = t & 31;
  float v = s[(size_t)g * DD + d];
  float s2 = v * v;
#pragma unroll
  for (int off = 16; off; off >>= 1) s2 += __shfl_xor(s2, off);
  float scale = s2 / ((1.0f + s2) * sqrtf(s2 + 1e-7f));
  float vd = scale * v;
  if (mode == 2)      out[(size_t)g * DD + d] = vd;
  else if (mode == 0) V[(size_t)g * DD + d] = vd;
  else                V[(size_t)g * DD + d] += vd;
}

// ---------------------------------------------------------------------------
extern "C" void kernel_launch(void* const* d_in, const int* in_sizes, int n_in,
                              void* d_out, int out_size, void* d_ws, size_t ws_size,
                              hipStream_t stream) {
  const float* x = (const float*)d_in[0];
  const float* W = (const float*)d_in[1];
  float* out = (float*)d_out;
  char* ws = (char*)d_ws;
  // Wb 134217728 | sPart 33554432 | C 16777216 | part2 2097152 | V 262144
  // Vb 131072  => 187039744
  const size_t NEED_NEW = 187039744ull;

  if (ws_size >= NEED_NEW) {
    unsigned short* Wb = (unsigned short*)ws;
    float* sPart = (float*)(ws + 134217728);
    float* Cbuf  = (float*)(ws + 167772160);
    float* part2 = (float*)(ws + 184549376);
    float* V     = (float*)(ws + 186646528);
    unsigned short* Vb = (unsigned short*)(ws + 186908672);
    for (int r = 0; r < 3; ++r) {
      if (r == 0) {
        caps_accum0<<<1024, 256, 0, stream>>>(x, W, Wb, sPart);
      } else {
        caps_logits<<<2048, 256, 0, stream>>>(x, Wb, Vb, Cbuf);
        caps_accum12<<<1024, 256, 0, stream>>>(x, Wb, Cbuf, sPart);
      }
      caps_reduce1<<<512, 256, 0, stream>>>((const float4*)sPart, (float4*)part2);
      caps_redsq<<<64, 256, 0, stream>>>((const float4*)part2, V, Vb, out,
                                         r == 2 ? 2 : (r == 0 ? 0 : 1));
    }
  } else {
    float* s     = (float*)ws;
    float* V     = s + 65536;
    float* sPart = V + 65536;
    const size_t need1 = (2ull * 65536 + 512ull * 8192) * 4;
    const int usePart = (ws_size >= need1) ? 1 : 0;
    for (int r = 0; r < 3; ++r) {
      if (!usePart) fb_zero<<<256, 256, 0, stream>>>(s);
      fb_pass<<<512, 1024, 0, stream>>>(x, W, V, s, sPart, r, usePart);
      if (usePart)
        fb_reduceS<<<64, 256, 0, stream>>>((const float4*)sPart, (float4*)s);
      fb_squash<<<256, 256, 0, stream>>>(s, V, out, r == 2 ? 2 : (r == 0 ? 0 : 1));
    }
  }
}

// Round 11
// 406.644 us; speedup vs baseline: 1.1951x; 1.1951x over previous
//
#include <hip/hip_runtime.h>
#include <cstddef>
#include <cstdint>

typedef short  bf16x8 __attribute__((ext_vector_type(8)));
typedef float  f32x16 __attribute__((ext_vector_type(16)));

#define IC 2048
#define JD 16
#define NC 64
#define DD 32
#define ICH 16                 // i per accum block
#define NPG (IC / ICH)         // 128 sPart pages

// ---------------------------------------------------------------- helpers ---
__device__ __forceinline__ unsigned f2bf1(float f) {          // RNE f32->bf16
  unsigned u = __float_as_uint(f);
  return (u + 0x7FFFu + ((u >> 16) & 1u)) >> 16;
}
__device__ __forceinline__ unsigned pk2(float lo, float hi) { // 2 bf16 in u32
  return f2bf1(lo) | (f2bf1(hi) << 16);
}
__device__ __forceinline__ float bflo(unsigned v) { return __uint_as_float(v << 16); }
__device__ __forceinline__ float bfhi(unsigned v) { return __uint_as_float(v & 0xFFFF0000u); }

template<int CTRL>
__device__ __forceinline__ float dpp_mov_f(float v) {
  int x = __builtin_amdgcn_mov_dpp(__float_as_int(v), CTRL, 0xf, 0xf, true);
  return __int_as_float(x);
}
__device__ __forceinline__ float row16_sum(float v) {
  v += dpp_mov_f<0x121>(v);
  v += dpp_mov_f<0x122>(v);
  v += dpp_mov_f<0x124>(v);
  v += dpp_mov_f<0x128>(v);
  return v;
}

// async global->LDS, 16B/lane: LDS dest = wave-uniform base + lane*16;
// global src is per-lane (pre-swizzled where needed).
__device__ __forceinline__ void gload16(const void* g, void* l) {
  __builtin_amdgcn_global_load_lds(
      (const __attribute__((address_space(1))) unsigned int*)g,
      (__attribute__((address_space(3))) unsigned int*)l, 16, 0, 0);
}

// ========================================================= MFMA path ========
// Wb layout (linear fragment order): row(n,i) = 512 ushort; granule l (16B)
// = W[n][i][d=l&31][j=(l>>5)*8..+8] bf16.

// accum r0 + W f32->bf16 conversion. m97 shape: block-wide dbuf tile +
// barrier per phase. grid 1024 = 128 ic x 8 nq, 256 thr (4 waves).
// Wave w owns tile rows 2w, 2w+1 (n0 = nq*8+2w) and stages them itself.
__global__ __launch_bounds__(256, 3) void caps_accum0(
    const float* __restrict__ x, const float* __restrict__ Wf,
    unsigned short* __restrict__ Wb, float* __restrict__ sPart)
{
  const int t = threadIdx.x, w = t >> 6, l = t & 63;
  const int m = l & 31, h = l >> 5;
  const int ic = blockIdx.x >> 3, nq = blockIdx.x & 7;
  const int i0 = ic * ICH;
  const int n0 = nq * 8 + 2 * w;
  __shared__ __align__(16) float wtf[2][8][512];             // 32 KB dbuf
  __shared__ __align__(16) unsigned short xlg[ICH][512];     // 16 KB

  // perm-swizzled f32 source: consumer lane c reads LDS bytes c*32..+32
  // (f32 idx c*8) = W f32 idx (c&31)*16 + (c>>5)*8 .. +8.
  const int pl = l >> 1, ph = l & 1;
  const size_t sA = (size_t)pl * 16 + ph * 4;        // covers lanes 0..31 (h=0)
  const size_t sB = (size_t)pl * 16 + 8 + ph * 4;    // covers lanes 32..63 (h=1)
#define ST0(B, IL) { \
    size_t r0 = ((size_t)n0 * IC + (i0 + (IL))) << 9; \
    size_t r1 = ((size_t)(n0 + 1) * IC + (i0 + (IL))) << 9; \
    gload16(Wf + r0 + sA, &wtf[B][2*w][0]); \
    gload16(Wf + r0 + sB, &wtf[B][2*w][256]); \
    gload16(Wf + r1 + sA, &wtf[B][2*w+1][0]); \
    gload16(Wf + r1 + sB, &wtf[B][2*w+1][256]); }

  ST0(0, 0)                                          // start HBM early
  for (int gg = t; gg < ICH * 64; gg += 256) {       // x -> bf16 frags
    int il = gg >> 6, ll = gg & 63;
    const float* xs = x + ((size_t)(ll & 31) * IC + (i0 + il)) * JD + (ll >> 5) * 8;
    float4 xa = *reinterpret_cast<const float4*>(xs);
    float4 xb = *reinterpret_cast<const float4*>(xs + 4);
    uint4 pv;
    pv.x = pk2(xa.x, xa.y); pv.y = pk2(xa.z, xa.w);
    pv.z = pk2(xb.x, xb.y); pv.w = pk2(xb.z, xb.w);
    *reinterpret_cast<uint4*>(&xlg[il][ll * 8]) = pv;
  }
  __syncthreads();                                   // drains gloads too

  f32x16 sacc0 = (f32x16)0.0f, sacc1 = (f32x16)0.0f;
  int cur = 0;
#pragma unroll
  for (int il = 0; il < ICH; ++il) {
    if (il + 1 < ICH) ST0(cur ^ 1, il + 1)           // stage next FIRST
    // consume current tile: lane l reads 8 f32 per row at f32 idx l*8
    float4 a0 = *reinterpret_cast<const float4*>(&wtf[cur][2*w][(size_t)l * 8]);
    float4 a1 = *reinterpret_cast<const float4*>(&wtf[cur][2*w][(size_t)l * 8 + 4]);
    float4 b0 = *reinterpret_cast<const float4*>(&wtf[cur][2*w+1][(size_t)l * 8]);
    float4 b1 = *reinterpret_cast<const float4*>(&wtf[cur][2*w+1][(size_t)l * 8 + 4]);
    uint4 pA, pB;
    pA.x = pk2(a0.x, a0.y); pA.y = pk2(a0.z, a0.w);
    pA.z = pk2(a1.x, a1.y); pA.w = pk2(a1.z, a1.w);
    pB.x = pk2(b0.x, b0.y); pB.y = pk2(b0.z, b0.w);
    pB.z = pk2(b1.x, b1.y); pB.w = pk2(b1.z, b1.w);
    *reinterpret_cast<uint4*>(Wb + (((size_t)n0 * IC + (i0 + il)) << 9) + (size_t)l * 8) = pA;
    *reinterpret_cast<uint4*>(Wb + (((size_t)(n0 + 1) * IC + (i0 + il)) << 9) + (size_t)l * 8) = pB;
    bf16x8 bfrag = *reinterpret_cast<const bf16x8*>(&xlg[il][(size_t)l * 8]);
    sacc0 = __builtin_amdgcn_mfma_f32_32x32x16_bf16(
        *reinterpret_cast<bf16x8*>(&pA), bfrag, sacc0, 0, 0, 0);
    sacc1 = __builtin_amdgcn_mfma_f32_32x32x16_bf16(
        *reinterpret_cast<bf16x8*>(&pB), bfrag, sacc1, 0, 0, 0);
    __syncthreads();                                 // m97 drain + swap
    cur ^= 1;
  }
#undef ST0
  float* page = sPart + (size_t)ic * 65536;          // [n][d/4][b][4]
#pragma unroll
  for (int q = 0; q < 4; ++q) {
    float4 v0 = make_float4(sacc0[4*q]*0.015625f, sacc0[4*q+1]*0.015625f,
                            sacc0[4*q+2]*0.015625f, sacc0[4*q+3]*0.015625f);
    float4 v1 = make_float4(sacc1[4*q]*0.015625f, sacc1[4*q+1]*0.015625f,
                            sacc1[4*q+2]*0.015625f, sacc1[4*q+3]*0.015625f);
    *reinterpret_cast<float4*>(page + (((size_t)n0*8 + 2*q+h)*32 + m)*4) = v0;
    *reinterpret_cast<float4*>(page + ((((size_t)n0+1)*8 + 2*q+h)*32 + m)*4) = v1;
  }
}

// logits (r>=1): grid 2048 (one i), 16 nn-phases, 1 gload/wave/phase.
// Writes C[i][n][b] = e/den.
__global__ __launch_bounds__(256, 6) void caps_logits(
    const float* __restrict__ x, const unsigned short* __restrict__ Wb,
    const unsigned short* __restrict__ Vb, float* __restrict__ C)
{
  const int t = threadIdx.x, w = t >> 6, l = t & 63;
  const int m = l & 31, h = l >> 5;
  const int i = blockIdx.x;
  __shared__ __align__(16) unsigned short wl[2][4][512];   // 8 KB dbuf
  __shared__ __align__(16) unsigned short xlg[512];        // 1 KB
  __shared__ float den4[4][32];
  __shared__ float denf[32];
#define STL(B, NN) gload16( \
    Wb + (((size_t)(w * 16 + (NN)) * IC + i) << 9) + (size_t)l * 8, &wl[B][w][0]);
  STL(0, 0)
  if (t < 64) {
    const float* xs = x + ((size_t)(t & 31) * IC + i) * JD + (t >> 5) * 8;
    float4 xa = *reinterpret_cast<const float4*>(xs);
    float4 xb = *reinterpret_cast<const float4*>(xs + 4);
    uint4 pv;
    pv.x = pk2(xa.x, xa.y); pv.y = pk2(xa.z, xa.w);
    pv.z = pk2(xb.x, xb.y); pv.w = pk2(xb.z, xb.w);
    *reinterpret_cast<uint4*>(&xlg[t * 8]) = pv;
  }
  __syncthreads();
  bf16x8 bfrag = *reinterpret_cast<const bf16x8*>(&xlg[(size_t)l * 8]);
  float e[16];
  float pden = 0.f;
  int cur = 0;
#pragma unroll
  for (int nn = 0; nn < 16; ++nn) {
    if (nn + 1 < 16) STL(cur ^ 1, nn + 1)
    bf16x8 af = *reinterpret_cast<const bf16x8*>(&wl[cur][w][(size_t)l * 8]);
    const int n = w * 16 + nn;
    f32x16 u = __builtin_amdgcn_mfma_f32_32x32x16_bf16(
        af, bfrag, (f32x16)0.0f, 0, 0, 0);
    float partial = 0.f;
    const unsigned short* vrow = Vb + ((size_t)m * NC + n) * DD;
#pragma unroll
    for (int q = 0; q < 4; ++q) {                // Vb is L2-hot (128 KB)
      uint2 vv = *reinterpret_cast<const uint2*>(vrow + (2 * q + h) * 4);
      partial += bflo(vv.x) * u[4*q+0] + bfhi(vv.x) * u[4*q+1]
               + bflo(vv.y) * u[4*q+2] + bfhi(vv.y) * u[4*q+3];
    }
    float logit = partial + __shfl_xor(partial, 32);
    e[nn] = __expf(logit);   // |logit| small (V squashed); shift-invariant
    pden += e[nn];
    __syncthreads();
    cur ^= 1;
  }
#undef STL
  if (h == 0) den4[w][m] = pden;
  __syncthreads();
  if (t < 32) denf[t] = 1.0f / (den4[0][t] + den4[1][t] + den4[2][t] + den4[3][t]);
  __syncthreads();
  if (h == 0) {
    float rden = denf[m];
    float* crow = C + ((size_t)i * NC + w * 16) * 32 + m;
#pragma unroll
    for (int nn = 0; nn < 16; ++nn) crow[nn * 32] = e[nn] * rden;
  }
}

// accum r1/r2: weighted GEMM on Wb, m97 shape. Wave w stages tile rows w, w+4;
// consumes rows 2w, 2w+1.
__global__ __launch_bounds__(256, 3) void caps_accum12(
    const float* __restrict__ x, const unsigned short* __restrict__ Wb,
    const float* __restrict__ C, float* __restrict__ sPart)
{
  const int t = threadIdx.x, w = t >> 6, l = t & 63;
  const int m = l & 31, h = l >> 5;
  const int ic = blockIdx.x >> 3, nq = blockIdx.x & 7;
  const int i0 = ic * ICH;
  const int n0 = nq * 8 + 2 * w;
  __shared__ __align__(16) unsigned short wt[2][8][512];   // 16 KB dbuf
  __shared__ __align__(16) unsigned short xlg[ICH][512];   // 16 KB
  __shared__ float Cl[ICH][8][32];                         // 16 KB
#define ST12(B, IL) { \
    gload16(Wb + (((size_t)(nq*8 + w)     * IC + (i0 + (IL))) << 9) + (size_t)l * 8, &wt[B][w][0]); \
    gload16(Wb + (((size_t)(nq*8 + w + 4) * IC + (i0 + (IL))) << 9) + (size_t)l * 8, &wt[B][w + 4][0]); }
  ST12(0, 0)
  for (int gg = t; gg < ICH * 64; gg += 256) {
    int il = gg >> 6, ll = gg & 63;
    const float* xs = x + ((size_t)(ll & 31) * IC + (i0 + il)) * JD + (ll >> 5) * 8;
    float4 xa = *reinterpret_cast<const float4*>(xs);
    float4 xb = *reinterpret_cast<const float4*>(xs + 4);
    uint4 pv;
    pv.x = pk2(xa.x, xa.y); pv.y = pk2(xa.z, xa.w);
    pv.z = pk2(xb.x, xb.y); pv.w = pk2(xb.z, xb.w);
    *reinterpret_cast<uint4*>(&xlg[il][ll * 8]) = pv;
  }
  for (int f = t; f < ICH * 64; f += 256) {          // C tile: 1024 float4
    int il = f >> 6, nn = (f >> 3) & 7, mq = f & 7;
    *reinterpret_cast<float4*>(&Cl[il][nn][mq * 4]) =
        *reinterpret_cast<const float4*>(
            C + (((size_t)(i0 + il) * NC + nq * 8 + nn)) * 32 + mq * 4);
  }
  __syncthreads();

  f32x16 sacc0 = (f32x16)0.0f, sacc1 = (f32x16)0.0f;
  int cur = 0;
#pragma unroll
  for (int il = 0; il < ICH; ++il) {
    if (il + 1 < ICH) ST12(cur ^ 1, il + 1)
    bf16x8 af0 = *reinterpret_cast<const bf16x8*>(&wt[cur][2*w][(size_t)l * 8]);
    bf16x8 af1 = *reinterpret_cast<const bf16x8*>(&wt[cur][2*w+1][(size_t)l * 8]);
    bf16x8 bfrag = *reinterpret_cast<const bf16x8*>(&xlg[il][(size_t)l * 8]);
    float c0 = Cl[il][2*w][m];
    float c1 = Cl[il][2*w+1][m];
    f32x16 u0 = __builtin_amdgcn_mfma_f32_32x32x16_bf16(
        af0, bfrag, (f32x16)0.0f, 0, 0, 0);
    f32x16 u1 = __builtin_amdgcn_mfma_f32_32x32x16_bf16(
        af1, bfrag, (f32x16)0.0f, 0, 0, 0);
#pragma unroll
    for (int k = 0; k < 16; ++k) {
      sacc0[k] += c0 * u0[k];
      sacc1[k] += c1 * u1[k];
    }
    __syncthreads();
    cur ^= 1;
  }
#undef ST12
  float* page = sPart + (size_t)ic * 65536;
#pragma unroll
  for (int q = 0; q < 4; ++q) {
    float4 v0 = make_float4(sacc0[4*q], sacc0[4*q+1], sacc0[4*q+2], sacc0[4*q+3]);
    float4 v1 = make_float4(sacc1[4*q], sacc1[4*q+1], sacc1[4*q+2], sacc1[4*q+3]);
    *reinterpret_cast<float4*>(page + (((size_t)n0*8 + 2*q+h)*32 + m)*4) = v0;
    *reinterpret_cast<float4*>(page + ((((size_t)n0+1)*8 + 2*q+h)*32 + m)*4) = v1;
  }
}

// reduce level 1: 128 pages -> 8 partial pages
__global__ __launch_bounds__(256) void caps_reduce1(
    const float4* __restrict__ sPart, float4* __restrict__ part2) {
  int blk = blockIdx.x;              // 512 = 8 pg x 64 fb
  int pg = blk >> 6, fb = blk & 63;
  int fid = fb * 256 + threadIdx.x;  // 0..16383
  float4 a = make_float4(0.f, 0.f, 0.f, 0.f);
#pragma unroll 8
  for (int p = 0; p < 16; ++p) {
    float4 v = sPart[(size_t)(pg * 16 + p) * 16384 + fid];
    a.x += v.x; a.y += v.y; a.z += v.z; a.w += v.w;
  }
  part2[(size_t)pg * 16384 + fid] = a;
}

// fused reduce level 2 + squash; emits V (f32) and Vb (bf16).
__global__ __launch_bounds__(256) void caps_redsq(
    const float4* __restrict__ part2, float* __restrict__ V,
    unsigned short* __restrict__ Vb, float* __restrict__ out, int mode)
{
  const int n = blockIdx.x, t = threadIdx.x;
  const int dc = t >> 5, b = t & 31;
  const int fid = n * 256 + t;
  __shared__ float sq[8][32];
  float4 a = make_float4(0.f, 0.f, 0.f, 0.f);
#pragma unroll
  for (int pg = 0; pg < 8; ++pg) {
    float4 v = part2[(size_t)pg * 16384 + fid];
    a.x += v.x; a.y += v.y; a.z += v.z; a.w += v.w;
  }
  sq[dc][b] = a.x*a.x + a.y*a.y + a.z*a.z + a.w*a.w;
  __syncthreads();
  float s2 = 0.f;
#pragma unroll
  for (int q = 0; q < 8; ++q) s2 += sq[q][b];
  float scale = s2 / ((1.0f + s2) * sqrtf(s2 + 1e-7f));
  float4 vd = make_float4(a.x*scale, a.y*scale, a.z*scale, a.w*scale);
  const size_t off = ((size_t)b * NC + n) * DD + dc * 4;
  if (mode == 2) {
    *reinterpret_cast<float4*>(out + off) = vd;
  } else {
    float4 nv = vd;
    if (mode == 1) {
      float4 old = *reinterpret_cast<const float4*>(V + off);
      nv.x += old.x; nv.y += old.y; nv.z += old.z; nv.w += old.w;
    }
    *reinterpret_cast<float4*>(V + off) = nv;
    uint2 pb;
    pb.x = pk2(nv.x, nv.y);
    pb.y = pk2(nv.z, nv.w);
    *reinterpret_cast<uint2*>(Vb + off) = pb;
  }
}

// ============================== fallback: R6 f32 path (ws too small) ========
__global__ void fb_zero(float* __restrict__ s) {
  s[blockIdx.x * 256 + threadIdx.x] = 0.0f;
}
__global__ __launch_bounds__(1024, 4)
void fb_pass(const float* __restrict__ x, const float* __restrict__ W,
             const float* __restrict__ V, float* __restrict__ sOut,
             float* __restrict__ sPart, int r, int usePart)
{
  const int t = threadIdx.x, w = t >> 6, l = t & 63;
  const int n = (w << 2) | (l >> 4);
  const int d0 = (l & 15) << 1;
  const int blk = blockIdx.x, xcd = blk & 7, slot = blk >> 3;
  const int ic = xcd * 8 + (slot >> 3), bq = slot & 7;
  const int i0 = ic * 32, bbase = bq * 4;
  __shared__ float den[2][4];
  __shared__ float Vlds[4 * NC * DD];
  if (r != 0) {
    const float4* src = reinterpret_cast<const float4*>(V + (size_t)bbase * 2048);
    float4* dst = reinterpret_cast<float4*>(Vlds);
    dst[t] = src[t]; dst[t + 1024] = src[t + 1024];
  }
  float acc0[4], acc1[4];
#pragma unroll
  for (int b = 0; b < 4; ++b) { acc0[b] = 0.f; acc1[b] = 0.f; }
  for (int ii = 0; ii < 32; ++ii) {
    const int i = i0 + ii, p = ii & 1;
    const float4* Wp = reinterpret_cast<const float4*>(
        W + (((size_t)n * IC + i) * DD + d0) * JD);
    float4 wr[8];
#pragma unroll
    for (int q = 0; q < 8; ++q) wr[q] = Wp[q];
    if (r == 0) {
#pragma unroll
      for (int bb = 0; bb < 4; ++bb) {
        const float* xp = x + ((size_t)(bbase + bb) * IC + i) * JD;
        float u0 = 0.f, u1 = 0.f;
#pragma unroll
        for (int q = 0; q < 4; ++q) {
          float4 w0 = wr[q], w1 = wr[4 + q];
          float x0 = xp[4*q], x1 = xp[4*q+1], x2 = xp[4*q+2], x3 = xp[4*q+3];
          u0 += w0.x*x0 + w0.y*x1 + w0.z*x2 + w0.w*x3;
          u1 += w1.x*x0 + w1.y*x1 + w1.z*x2 + w1.w*x3;
        }
        acc0[bb] += u0 * 0.015625f; acc1[bb] += u1 * 0.015625f;
      }
    } else {
      if (t < 4) den[p][t] = 0.0f;
      __syncthreads();
      float p0a[4], p1a[4];
#pragma unroll
      for (int bb = 0; bb < 4; ++bb) {
        const float* xp = x + ((size_t)(bbase + bb) * IC + i) * JD;
        float u0 = 0.f, u1 = 0.f;
#pragma unroll
        for (int q = 0; q < 4; ++q) {
          float4 w0 = wr[q], w1 = wr[4 + q];
          float x0 = xp[4*q], x1 = xp[4*q+1], x2 = xp[4*q+2], x3 = xp[4*q+3];
          u0 += w0.x*x0 + w0.y*x1 + w0.z*x2 + w0.w*x3;
          u1 += w1.x*x0 + w1.y*x1 + w1.z*x2 + w1.w*x3;
        }
        const float2 vv = *reinterpret_cast<const float2*>(
            &Vlds[((size_t)bb * NC + n) * DD + d0]);
        float lp = u0 * vv.x + u1 * vv.y;
        float logit = row16_sum(lp);
        float e = __expf(logit);
        p0a[bb] = e * u0; p1a[bb] = e * u1;
        float es = e + __shfl_xor(e, 16);
        es += __shfl_xor(es, 32);
        if (l == 0) atomicAdd(&den[p][bb], es);
      }
      __syncthreads();
#pragma unroll
      for (int bb = 0; bb < 4; ++bb) {
        float rd = 1.0f / den[p][bb];
        acc0[bb] += p0a[bb] * rd; acc1[bb] += p1a[bb] * rd;
      }
    }
  }
  if (usePart) {
#pragma unroll
    for (int bb = 0; bb < 4; ++bb) {
      float2 v2 = make_float2(acc0[bb], acc1[bb]);
      size_t off = (((size_t)(bq * 64 + ic) * 4 + bb) * NC + n) * DD + d0;
      *reinterpret_cast<float2*>(sPart + off) = v2;
    }
  } else {
#pragma unroll
    for (int bb = 0; bb < 4; ++bb) {
      float* sp = sOut + ((size_t)(bbase + bb) * NC + n) * DD + d0;
      atomicAdd(sp, acc0[bb]); atomicAdd(sp + 1, acc1[bb]);
    }
  }
}
__global__ void fb_reduceS(const float4* __restrict__ sPart, float4* __restrict__ s) {
  int q = blockIdx.x * 256 + threadIdx.x;
  int bq = q >> 11, qq = q & 2047;
  float4 sum = make_float4(0.f, 0.f, 0.f, 0.f);
#pragma unroll 8
  for (int p = 0; p < 64; ++p) {
    float4 v = sPart[(size_t)(bq * 64 + p) * 2048 + qq];
    sum.x += v.x; sum.y += v.y; sum.z += v.z; sum.w += v.w;
  }
  s[q] = sum;
}
__global__ void fb_squash(const float* __restrict__ s, float* __restrict__ V,
                          float* __restrict__ out, int mode)
{
  const int t = threadIdx.x;
  const int g = blockIdx.x * 8 + (t >> 5);
  const int d = t & 31;
  float v = s[(size_t)g * DD + d];
  float s2 = v * v;
#pragma unroll
  for (int off = 16; off; off >>= 1) s2 += __shfl_xor(s2, off);
  float scale = s2 / ((1.0f + s2) * sqrtf(s2 + 1e-7f));
  float vd = scale * v;
  if (mode == 2)      out[(size_t)g * DD + d] = vd;
  else if (mode == 0) V[(size_t)g * DD + d] = vd;
  else                V[(size_t)g * DD + d] += vd;
}

// ---------------------------------------------------------------------------
extern "C" void kernel_launch(void* const* d_in, const int* in_sizes, int n_in,
                              void* d_out, int out_size, void* d_ws, size_t ws_size,
                              hipStream_t stream) {
  const float* x = (const float*)d_in[0];
  const float* W = (const float*)d_in[1];
  float* out = (float*)d_out;
  char* ws = (char*)d_ws;
  // Wb 134217728 | sPart 33554432 | C 16777216 | part2 2097152 | V 262144
  // Vb 131072  => 187039744
  const size_t NEED_NEW = 187039744ull;

  if (ws_size >= NEED_NEW) {
    unsigned short* Wb = (unsigned short*)ws;
    float* sPart = (float*)(ws + 134217728);
    float* Cbuf  = (float*)(ws + 167772160);
    float* part2 = (float*)(ws + 184549376);
    float* V     = (float*)(ws + 186646528);
    unsigned short* Vb = (unsigned short*)(ws + 186908672);
    for (int r = 0; r < 3; ++r) {
      if (r == 0) {
        caps_accum0<<<1024, 256, 0, stream>>>(x, W, Wb, sPart);
      } else {
        caps_logits<<<2048, 256, 0, stream>>>(x, Wb, Vb, Cbuf);
        caps_accum12<<<1024, 256, 0, stream>>>(x, Wb, Cbuf, sPart);
      }
      caps_reduce1<<<512, 256, 0, stream>>>((const float4*)sPart, (float4*)part2);
      caps_redsq<<<64, 256, 0, stream>>>((const float4*)part2, V, Vb, out,
                                         r == 2 ? 2 : (r == 0 ? 0 : 1));
    }
  } else {
    float* s     = (float*)ws;
    float* V     = s + 65536;
    float* sPart = V + 65536;
    const size_t need1 = (2ull * 65536 + 512ull * 8192) * 4;
    const int usePart = (ws_size >= need1) ? 1 : 0;
    for (int r = 0; r < 3; ++r) {
      if (!usePart) fb_zero<<<256, 256, 0, stream>>>(s);
      fb_pass<<<512, 1024, 0, stream>>>(x, W, V, s, sPart, r, usePart);
      if (usePart)
        fb_reduceS<<<64, 256, 0, stream>>>((const float4*)sPart, (float4*)s);
      fb_squash<<<256, 256, 0, stream>>>(s, V, out, r == 2 ? 2 : (r == 0 ? 0 : 1));
    }
  }
}

// Round 12
// 301.628 us; speedup vs baseline: 1.6111x; 1.3482x over previous
//
#include <hip/hip_runtime.h>
#include <cstddef>
#include <cstdint>

typedef short  bf16x8 __attribute__((ext_vector_type(8)));
typedef float  f32x16 __attribute__((ext_vector_type(16)));

#define IC 2048
#define JD 16
#define NC 64
#define DD 32

// ---------------------------------------------------------------- helpers ---
__device__ __forceinline__ unsigned f2bf1(float f) {          // RNE f32->bf16
  unsigned u = __float_as_uint(f);
  return (u + 0x7FFFu + ((u >> 16) & 1u)) >> 16;
}
__device__ __forceinline__ unsigned pk2(float lo, float hi) { // 2 bf16 in u32
  return f2bf1(lo) | (f2bf1(hi) << 16);
}
__device__ __forceinline__ float bflo(unsigned v) { return __uint_as_float(v << 16); }
__device__ __forceinline__ float bfhi(unsigned v) { return __uint_as_float(v & 0xFFFF0000u); }

template<int CTRL>
__device__ __forceinline__ float dpp_mov_f(float v) {
  int x = __builtin_amdgcn_mov_dpp(__float_as_int(v), CTRL, 0xf, 0xf, true);
  return __int_as_float(x);
}
__device__ __forceinline__ float row16_sum(float v) {
  v += dpp_mov_f<0x121>(v);
  v += dpp_mov_f<0x122>(v);
  v += dpp_mov_f<0x124>(v);
  v += dpp_mov_f<0x128>(v);
  return v;
}

// ===================================================== streaming MFMA path ==
// Wb fragment-order: row r = n*IC+i (131072 rows x 512 ushort = 1KB).
// Lane l's granule Wb[r*512 + l*8 .. +8] = bf16 W[n][i][d=l&31][j=(l>>5)*8..+8].
// xb: same per-row fragment order for x: row i, lane l -> x[b=l&31][i][j=...].
// Vb2: [n][dc(0..7)][b(0..31)][4] bf16 (dc = d/4) -> contiguous dot loads.
// eC: [i][n][b] f32 raw exp; denP: [i][half(2)][b] f32 partial denominators.

// x -> xb (4 MB -> 2 MB), one granule per thread. grid 512 x 256.
__global__ __launch_bounds__(256) void xb_conv(
    const float* __restrict__ x, unsigned short* __restrict__ xb)
{
  int gid = blockIdx.x * 256 + threadIdx.x;      // 131072
  int i = gid >> 6, l = gid & 63;
  const float* xs = x + ((size_t)(l & 31) * IC + i) * JD + (l >> 5) * 8;
  float4 a = *reinterpret_cast<const float4*>(xs);
  float4 b = *reinterpret_cast<const float4*>(xs + 4);
  uint4 p;
  p.x = pk2(a.x, a.y); p.y = pk2(a.z, a.w);
  p.z = pk2(b.x, b.y); p.w = pk2(b.z, b.w);
  *reinterpret_cast<uint4*>(xb + (size_t)i * 512 + l * 8) = p;
}

// W f32 -> Wb bf16 fragment-order. Contiguous reads (thread k: row + k*32B),
// permuted-within-1KB writes. Grid-stride, no barriers. grid 4096 x 256.
__global__ __launch_bounds__(256) void w_conv(
    const float* __restrict__ Wf, unsigned short* __restrict__ Wb)
{
  const size_t stride = (size_t)gridDim.x * 256;
  for (size_t g = (size_t)blockIdx.x * 256 + threadIdx.x; g < 8388608ull;
       g += stride) {
    size_t r = g >> 6; int k = (int)(g & 63);
    const float* src = Wf + r * 512 + (size_t)k * 8;   // contiguous 32B/lane
    float4 a = *reinterpret_cast<const float4*>(src);
    float4 b = *reinterpret_cast<const float4*>(src + 4);
    uint4 p;
    p.x = pk2(a.x, a.y); p.y = pk2(a.z, a.w);
    p.z = pk2(b.x, b.y); p.w = pk2(b.z, b.w);
    // src f32 idx k*8 = d*16+j -> d=k>>1, j0=(k&1)*8 -> dest lane (j0/8)*32+d
    int ld = ((k & 1) << 5) | (k >> 1);
    *reinterpret_cast<uint4*>(Wb + r * 512 + (size_t)ld * 8) = p;
  }
}

// logits (r>=1): wave owns (i, n-half of 32). Barrier-free stream of 32
// contiguous 1KB afrag rows; stores RAW e and per-half den partial.
// grid 1024 x 256 (4 waves) = 4096 waves.
__global__ __launch_bounds__(256) void caps_logits(
    const unsigned short* __restrict__ xb, const unsigned short* __restrict__ Wb,
    const unsigned short* __restrict__ Vb2, float* __restrict__ eC,
    float* __restrict__ denP)
{
  const int t = threadIdx.x, w = t >> 6, l = t & 63;
  const int m = l & 31, h = l >> 5;
  const int Wv = blockIdx.x * 4 + w;             // 0..4095
  const int i = Wv >> 1, half = Wv & 1;
  const int n0 = half * 32;
  bf16x8 bfrag = *reinterpret_cast<const bf16x8*>(xb + (size_t)i * 512 + l * 8);
  float pden = 0.f;
#pragma unroll 2
  for (int nn = 0; nn < 32; ++nn) {
    const int n = n0 + nn;
    bf16x8 af = *reinterpret_cast<const bf16x8*>(
        Wb + ((size_t)n * IC + i) * 512 + l * 8);        // contiguous 1KB/wave
    f32x16 u = __builtin_amdgcn_mfma_f32_32x32x16_bf16(
        af, bfrag, (f32x16)0.0f, 0, 0, 0);
    float partial = 0.f;
    const unsigned short* vr = Vb2 + (size_t)n * 1024;
#pragma unroll
    for (int q = 0; q < 4; ++q) {                // contiguous 256B per chunk
      uint2 vv = *reinterpret_cast<const uint2*>(vr + ((2*q+h) * 32 + m) * 4);
      partial += bflo(vv.x) * u[4*q+0] + bfhi(vv.x) * u[4*q+1]
               + bflo(vv.y) * u[4*q+2] + bfhi(vv.y) * u[4*q+3];
    }
    float logit = partial + __shfl_xor(partial, 32);
    // |logit| small (V squashed): exp safe w/o max-sub; shift-invariant.
    float e = __expf(logit);
    pden += e;
    if (h == 0) eC[(size_t)i * 2048 + n * 32 + m] = e;   // 128B contiguous
  }
  if (h == 0) denP[(size_t)i * 64 + half * 32 + m] = pden;
}

// accum (all rounds; r0 uses c = 1/64 exactly). Wave owns (n, i-chunk of 32):
// afrag stream = 32 KB FULLY CONTIGUOUS Wb. No LDS, no barriers.
// grid 1024 x 256 = 4096 waves.
__global__ __launch_bounds__(256) void caps_accum(
    const unsigned short* __restrict__ xb, const unsigned short* __restrict__ Wb,
    const float* __restrict__ eC, const float* __restrict__ denP,
    float* __restrict__ sPart, int r)
{
  const int t = threadIdx.x, w = t >> 6, l = t & 63;
  const int m = l & 31, h = l >> 5;
  const int Wv = blockIdx.x * 4 + w;             // 0..4095
  const int n = Wv & 63, ch = Wv >> 6;
  const int i0 = ch * 32;
  const unsigned short* wrow = Wb + ((size_t)n * IC + i0) * 512 + l * 8;
  const unsigned short* xrow = xb + (size_t)i0 * 512 + l * 8;
  f32x16 sacc = (f32x16)0.0f;
#pragma unroll 4
  for (int ii = 0; ii < 32; ++ii) {
    bf16x8 af = *reinterpret_cast<const bf16x8*>(wrow + (size_t)ii * 512);
    bf16x8 bf = *reinterpret_cast<const bf16x8*>(xrow + (size_t)ii * 512);
    f32x16 u = __builtin_amdgcn_mfma_f32_32x32x16_bf16(
        af, bf, (f32x16)0.0f, 0, 0, 0);
    float c;
    if (r == 0) {
      c = 0.015625f;                             // softmax of zeros = 1/64
    } else {
      float e  = eC[(size_t)(i0 + ii) * 2048 + n * 32 + m];
      float dp = denP[(size_t)(i0 + ii) * 64 + m]
               + denP[(size_t)(i0 + ii) * 64 + 32 + m];
      c = e / dp;
    }
#pragma unroll
    for (int k = 0; k < 16; ++k) sacc[k] += c * u[k];
  }
  // page p = n*64+ch: [dc][b][4] f32 = 4 KB
  float* page = sPart + ((size_t)n * 64 + ch) * 1024;
#pragma unroll
  for (int q = 0; q < 4; ++q) {
    float4 v = make_float4(sacc[4*q], sacc[4*q+1], sacc[4*q+2], sacc[4*q+3]);
    *reinterpret_cast<float4*>(page + ((2*q+h) * 32 + m) * 4) = v;
  }
}

// fused 64-page reduce + squash; emits V (f32), Vb2 (bf16) or out.
// grid 64 (n) x 256 (t = dc*32 + b).
__global__ __launch_bounds__(256) void caps_redsq(
    const float4* __restrict__ sPart, float* __restrict__ V,
    unsigned short* __restrict__ Vb2, float* __restrict__ out, int mode)
{
  const int n = blockIdx.x, t = threadIdx.x;
  const int dc = t >> 5, b = t & 31;
  __shared__ float sq[8][32];
  const float4* base = sPart + (size_t)n * 64 * 256 + t;   // page = 256 float4
  float4 a = make_float4(0.f, 0.f, 0.f, 0.f);
#pragma unroll 8
  for (int ch = 0; ch < 64; ++ch) {
    float4 v = base[(size_t)ch * 256];
    a.x += v.x; a.y += v.y; a.z += v.z; a.w += v.w;
  }
  sq[dc][b] = a.x*a.x + a.y*a.y + a.z*a.z + a.w*a.w;
  __syncthreads();
  float s2 = 0.f;
#pragma unroll
  for (int q = 0; q < 8; ++q) s2 += sq[q][b];
  float scale = s2 / ((1.0f + s2) * sqrtf(s2 + 1e-7f));
  float4 vd = make_float4(a.x*scale, a.y*scale, a.z*scale, a.w*scale);
  const size_t off = ((size_t)b * NC + n) * DD + dc * 4;   // V/out [b][n][d]
  if (mode == 2) {
    *reinterpret_cast<float4*>(out + off) = vd;
  } else {
    float4 nv = vd;
    if (mode == 1) {
      float4 old = *reinterpret_cast<const float4*>(V + off);
      nv.x += old.x; nv.y += old.y; nv.z += old.z; nv.w += old.w;
    }
    *reinterpret_cast<float4*>(V + off) = nv;
    uint2 pb;
    pb.x = pk2(nv.x, nv.y);
    pb.y = pk2(nv.z, nv.w);
    // Vb2[n][dc][b][4] bf16
    *reinterpret_cast<uint2*>(Vb2 + (size_t)n * 1024 + (dc * 32 + b) * 4) = pb;
  }
}

// ============================== fallback: R6 f32 path (ws too small) ========
__global__ void fb_zero(float* __restrict__ s) {
  s[blockIdx.x * 256 + threadIdx.x] = 0.0f;
}
__global__ __launch_bounds__(1024, 4)
void fb_pass(const float* __restrict__ x, const float* __restrict__ W,
             const float* __restrict__ V, float* __restrict__ sOut,
             float* __restrict__ sPart, int r, int usePart)
{
  const int t = threadIdx.x, w = t >> 6, l = t & 63;
  const int n = (w << 2) | (l >> 4);
  const int d0 = (l & 15) << 1;
  const int blk = blockIdx.x, xcd = blk & 7, slot = blk >> 3;
  const int ic = xcd * 8 + (slot >> 3), bq = slot & 7;
  const int i0 = ic * 32, bbase = bq * 4;
  __shared__ float den[2][4];
  __shared__ float Vlds[4 * NC * DD];
  if (r != 0) {
    const float4* src = reinterpret_cast<const float4*>(V + (size_t)bbase * 2048);
    float4* dst = reinterpret_cast<float4*>(Vlds);
    dst[t] = src[t]; dst[t + 1024] = src[t + 1024];
  }
  float acc0[4], acc1[4];
#pragma unroll
  for (int b = 0; b < 4; ++b) { acc0[b] = 0.f; acc1[b] = 0.f; }
  for (int ii = 0; ii < 32; ++ii) {
    const int i = i0 + ii, p = ii & 1;
    const float4* Wp = reinterpret_cast<const float4*>(
        W + (((size_t)n * IC + i) * DD + d0) * JD);
    float4 wr[8];
#pragma unroll
    for (int q = 0; q < 8; ++q) wr[q] = Wp[q];
    if (r == 0) {
#pragma unroll
      for (int bb = 0; bb < 4; ++bb) {
        const float* xp = x + ((size_t)(bbase + bb) * IC + i) * JD;
        float u0 = 0.f, u1 = 0.f;
#pragma unroll
        for (int q = 0; q < 4; ++q) {
          float4 w0 = wr[q], w1 = wr[4 + q];
          float x0 = xp[4*q], x1 = xp[4*q+1], x2 = xp[4*q+2], x3 = xp[4*q+3];
          u0 += w0.x*x0 + w0.y*x1 + w0.z*x2 + w0.w*x3;
          u1 += w1.x*x0 + w1.y*x1 + w1.z*x2 + w1.w*x3;
        }
        acc0[bb] += u0 * 0.015625f; acc1[bb] += u1 * 0.015625f;
      }
    } else {
      if (t < 4) den[p][t] = 0.0f;
      __syncthreads();
      float p0a[4], p1a[4];
#pragma unroll
      for (int bb = 0; bb < 4; ++bb) {
        const float* xp = x + ((size_t)(bbase + bb) * IC + i) * JD;
        float u0 = 0.f, u1 = 0.f;
#pragma unroll
        for (int q = 0; q < 4; ++q) {
          float4 w0 = wr[q], w1 = wr[4 + q];
          float x0 = xp[4*q], x1 = xp[4*q+1], x2 = xp[4*q+2], x3 = xp[4*q+3];
          u0 += w0.x*x0 + w0.y*x1 + w0.z*x2 + w0.w*x3;
          u1 += w1.x*x0 + w1.y*x1 + w1.z*x2 + w1.w*x3;
        }
        const float2 vv = *reinterpret_cast<const float2*>(
            &Vlds[((size_t)bb * NC + n) * DD + d0]);
        float lp = u0 * vv.x + u1 * vv.y;
        float logit = row16_sum(lp);
        float e = __expf(logit);
        p0a[bb] = e * u0; p1a[bb] = e * u1;
        float es = e + __shfl_xor(e, 16);
        es += __shfl_xor(es, 32);
        if (l == 0) atomicAdd(&den[p][bb], es);
      }
      __syncthreads();
#pragma unroll
      for (int bb = 0; bb < 4; ++bb) {
        float rd = 1.0f / den[p][bb];
        acc0[bb] += p0a[bb] * rd; acc1[bb] += p1a[bb] * rd;
      }
    }
  }
  if (usePart) {
#pragma unroll
    for (int bb = 0; bb < 4; ++bb) {
      float2 v2 = make_float2(acc0[bb], acc1[bb]);
      size_t off = (((size_t)(bq * 64 + ic) * 4 + bb) * NC + n) * DD + d0;
      *reinterpret_cast<float2*>(sPart + off) = v2;
    }
  } else {
#pragma unroll
    for (int bb = 0; bb < 4; ++bb) {
      float* sp = sOut + ((size_t)(bbase + bb) * NC + n) * DD + d0;
      atomicAdd(sp, acc0[bb]); atomicAdd(sp + 1, acc1[bb]);
    }
  }
}
__global__ void fb_reduceS(const float4* __restrict__ sPart, float4* __restrict__ s) {
  int q = blockIdx.x * 256 + threadIdx.x;
  int bq = q >> 11, qq = q & 2047;
  float4 sum = make_float4(0.f, 0.f, 0.f, 0.f);
#pragma unroll 8
  for (int p = 0; p < 64; ++p) {
    float4 v = sPart[(size_t)(bq * 64 + p) * 2048 + qq];
    sum.x += v.x; sum.y += v.y; sum.z += v.z; sum.w += v.w;
  }
  s[q] = sum;
}
__global__ void fb_squash(const float* __restrict__ s, float* __restrict__ V,
                          float* __restrict__ out, int mode)
{
  const int t = threadIdx.x;
  const int g = blockIdx.x * 8 + (t >> 5);
  const int d = t & 31;
  float v = s[(size_t)g * DD + d];
  float s2 = v * v;
#pragma unroll
  for (int off = 16; off; off >>= 1) s2 += __shfl_xor(s2, off);
  float scale = s2 / ((1.0f + s2) * sqrtf(s2 + 1e-7f));
  float vd = scale * v;
  if (mode == 2)      out[(size_t)g * DD + d] = vd;
  else if (mode == 0) V[(size_t)g * DD + d] = vd;
  else                V[(size_t)g * DD + d] += vd;
}

// ---------------------------------------------------------------------------
extern "C" void kernel_launch(void* const* d_in, const int* in_sizes, int n_in,
                              void* d_out, int out_size, void* d_ws, size_t ws_size,
                              hipStream_t stream) {
  const float* x = (const float*)d_in[0];
  const float* W = (const float*)d_in[1];
  float* out = (float*)d_out;
  char* ws = (char*)d_ws;
  // Wb 134217728 | xb 2097152 | eC 16777216 | denP 524288 | sPart 16777216
  // V 262144 | Vb2 131072  => 170786816
  const size_t NEED_NEW = 170786816ull;

  if (ws_size >= NEED_NEW) {
    unsigned short* Wb  = (unsigned short*)ws;
    unsigned short* xb  = (unsigned short*)(ws + 134217728);
    float* eC           = (float*)(ws + 136314880);
    float* denP         = (float*)(ws + 153092096);
    float* sPart        = (float*)(ws + 153616384);
    float* V            = (float*)(ws + 170393600);
    unsigned short* Vb2 = (unsigned short*)(ws + 170655744);

    xb_conv<<<512, 256, 0, stream>>>(x, xb);
    w_conv<<<4096, 256, 0, stream>>>(W, Wb);
    caps_accum<<<1024, 256, 0, stream>>>(xb, Wb, eC, denP, sPart, 0);
    caps_redsq<<<64, 256, 0, stream>>>((const float4*)sPart, V, Vb2, out, 0);
    for (int r = 1; r < 3; ++r) {
      caps_logits<<<1024, 256, 0, stream>>>(xb, Wb, Vb2, eC, denP);
      caps_accum<<<1024, 256, 0, stream>>>(xb, Wb, eC, denP, sPart, r);
      caps_redsq<<<64, 256, 0, stream>>>((const float4*)sPart, V, Vb2, out,
                                         r == 2 ? 2 : 1);
    }
  } else {
    float* s     = (float*)ws;
    float* V     = s + 65536;
    float* sPart = V + 65536;
    const size_t need1 = (2ull * 65536 + 512ull * 8192) * 4;
    const int usePart = (ws_size >= need1) ? 1 : 0;
    for (int r = 0; r < 3; ++r) {
      if (!usePart) fb_zero<<<256, 256, 0, stream>>>(s);
      fb_pass<<<512, 1024, 0, stream>>>(x, W, V, s, sPart, r, usePart);
      if (usePart)
        fb_reduceS<<<64, 256, 0, stream>>>((const float4*)sPart, (float4*)s);
      fb_squash<<<256, 256, 0, stream>>>(s, V, out, r == 2 ? 2 : (r == 0 ? 0 : 1));
    }
  }
}

// Round 13
// 242.639 us; speedup vs baseline: 2.0028x; 1.2431x over previous
//
#include <hip/hip_runtime.h>
#include <cstddef>
#include <cstdint>

typedef short  bf16x8 __attribute__((ext_vector_type(8)));
typedef float  f32x16 __attribute__((ext_vector_type(16)));

#define IC 2048
#define JD 16
#define NC 64
#define DD 32

// ---------------------------------------------------------------- helpers ---
__device__ __forceinline__ unsigned f2bf1(float f) {          // RNE f32->bf16
  unsigned u = __float_as_uint(f);
  return (u + 0x7FFFu + ((u >> 16) & 1u)) >> 16;
}
__device__ __forceinline__ unsigned pk2(float lo, float hi) { // 2 bf16 in u32
  return f2bf1(lo) | (f2bf1(hi) << 16);
}
__device__ __forceinline__ float bflo(unsigned v) { return __uint_as_float(v << 16); }
__device__ __forceinline__ float bfhi(unsigned v) { return __uint_as_float(v & 0xFFFF0000u); }

template<int CTRL>
__device__ __forceinline__ float dpp_mov_f(float v) {
  int x = __builtin_amdgcn_mov_dpp(__float_as_int(v), CTRL, 0xf, 0xf, true);
  return __int_as_float(x);
}
__device__ __forceinline__ float row16_sum(float v) {
  v += dpp_mov_f<0x121>(v);
  v += dpp_mov_f<0x122>(v);
  v += dpp_mov_f<0x124>(v);
  v += dpp_mov_f<0x128>(v);
  return v;
}

// ===================================================== streaming MFMA path ==
// Wb fragment-order: row r = n*IC+i (131072 rows x 512 ushort = 1KB).
// Lane l's granule Wb[r*512 + l*8 .. +8] = bf16 W[n][i][d=l&31][j=(l>>5)*8..+8].
// xb: same per-row fragment order for x: row i, lane l -> x[b=l&31][i][j=...].
// Vb2: [n][dc(0..7)][b(0..31)][4] bf16 (dc = d/4) -> contiguous dot loads.
// eC: [i][n][b] f32 raw exp; denP: [i][half(2)][b] f32 partial denominators.

// x -> xb (4 MB -> 2 MB), one granule per thread. grid 512 x 256.
__global__ __launch_bounds__(256) void xb_conv(
    const float* __restrict__ x, unsigned short* __restrict__ xb)
{
  int gid = blockIdx.x * 256 + threadIdx.x;      // 131072
  int i = gid >> 6, l = gid & 63;
  const float* xs = x + ((size_t)(l & 31) * IC + i) * JD + (l >> 5) * 8;
  float4 a = *reinterpret_cast<const float4*>(xs);
  float4 b = *reinterpret_cast<const float4*>(xs + 4);
  uint4 p;
  p.x = pk2(a.x, a.y); p.y = pk2(a.z, a.w);
  p.z = pk2(b.x, b.y); p.w = pk2(b.z, b.w);
  *reinterpret_cast<uint4*>(xb + (size_t)i * 512 + l * 8) = p;
}

// FUSED: W f32 -> Wb bf16 conversion + round-0 accumulation (c = 1/64 exact).
// Wave owns (n, i-chunk of 32): W f32 read CONTIGUOUS (lane l -> row+l*32B),
// Wb store = within-1KB permuted 16B/lane (full coverage -> coalesced, same
// pattern as R12 w_conv), own MFMA A-frag via 4 ds_bpermute pulls from lane
// src(l) (inverse of the store perm). sacc chained, scaled 1/64 at store.
// grid 1024 x 256 = 4096 waves. No barriers, no LDS arrays.
__global__ __launch_bounds__(256) void caps_conv0(
    const unsigned short* __restrict__ xb, const float* __restrict__ Wf,
    unsigned short* __restrict__ Wb, float* __restrict__ sPart)
{
  const int t = threadIdx.x, w = t >> 6, l = t & 63;
  const int m = l & 31, h = l >> 5;
  const int Wv = blockIdx.x * 4 + w;             // 0..4095
  const int n = Wv & 63, ch = Wv >> 6;
  const int i0 = ch * 32;
  // my loaded granule (f32 idx l*8 = d*16+j: d=l>>1, j0=(l&1)*8) belongs at
  // fragment position ld; my fragment comes from lane srcl (inverse perm).
  const int ld   = ((l & 1) << 5) | (l >> 1);
  const int srci = (((l & 31) << 1) | (l >> 5)) << 2;   // byte addr for bperm
  const float* wrow = Wf + ((size_t)n * IC + i0) * 512 + (size_t)l * 8;
  unsigned short* wbrow = Wb + ((size_t)n * IC + i0) * 512 + (size_t)ld * 8;
  const unsigned short* xrow = xb + (size_t)i0 * 512 + l * 8;
  f32x16 sacc = (f32x16)0.0f;
#pragma unroll 4
  for (int ii = 0; ii < 32; ++ii) {
    float4 a = *reinterpret_cast<const float4*>(wrow + (size_t)ii * 512);
    float4 b = *reinterpret_cast<const float4*>(wrow + (size_t)ii * 512 + 4);
    uint4 p;
    p.x = pk2(a.x, a.y); p.y = pk2(a.z, a.w);
    p.z = pk2(b.x, b.y); p.w = pk2(b.z, b.w);
    *reinterpret_cast<uint4*>(wbrow + (size_t)ii * 512) = p;   // frag-order Wb
    uint4 af;                                     // pull my fragment
    af.x = (unsigned)__builtin_amdgcn_ds_bpermute(srci, (int)p.x);
    af.y = (unsigned)__builtin_amdgcn_ds_bpermute(srci, (int)p.y);
    af.z = (unsigned)__builtin_amdgcn_ds_bpermute(srci, (int)p.z);
    af.w = (unsigned)__builtin_amdgcn_ds_bpermute(srci, (int)p.w);
    bf16x8 bf = *reinterpret_cast<const bf16x8*>(xrow + (size_t)ii * 512);
    sacc = __builtin_amdgcn_mfma_f32_32x32x16_bf16(
        *reinterpret_cast<bf16x8*>(&af), bf, sacc, 0, 0, 0);
  }
  float* page = sPart + ((size_t)n * 64 + ch) * 1024;   // [dc][b][4] = 4 KB
#pragma unroll
  for (int q = 0; q < 4; ++q) {
    float4 v = make_float4(sacc[4*q] * 0.015625f, sacc[4*q+1] * 0.015625f,
                           sacc[4*q+2] * 0.015625f, sacc[4*q+3] * 0.015625f);
    *reinterpret_cast<float4*>(page + ((2*q+h) * 32 + m) * 4) = v;
  }
}

// logits (r>=1): wave owns (i, n-half of 32). Barrier-free stream of 32
// contiguous 1KB afrag rows; stores RAW e and per-half den partial.
// grid 1024 x 256 (4 waves) = 4096 waves.
__global__ __launch_bounds__(256) void caps_logits(
    const unsigned short* __restrict__ xb, const unsigned short* __restrict__ Wb,
    const unsigned short* __restrict__ Vb2, float* __restrict__ eC,
    float* __restrict__ denP)
{
  const int t = threadIdx.x, w = t >> 6, l = t & 63;
  const int m = l & 31, h = l >> 5;
  const int Wv = blockIdx.x * 4 + w;             // 0..4095
  const int i = Wv >> 1, half = Wv & 1;
  const int n0 = half * 32;
  bf16x8 bfrag = *reinterpret_cast<const bf16x8*>(xb + (size_t)i * 512 + l * 8);
  float pden = 0.f;
#pragma unroll 2
  for (int nn = 0; nn < 32; ++nn) {
    const int n = n0 + nn;
    bf16x8 af = *reinterpret_cast<const bf16x8*>(
        Wb + ((size_t)n * IC + i) * 512 + l * 8);        // contiguous 1KB/wave
    f32x16 u = __builtin_amdgcn_mfma_f32_32x32x16_bf16(
        af, bfrag, (f32x16)0.0f, 0, 0, 0);
    float partial = 0.f;
    const unsigned short* vr = Vb2 + (size_t)n * 1024;
#pragma unroll
    for (int q = 0; q < 4; ++q) {                // contiguous 256B per chunk
      uint2 vv = *reinterpret_cast<const uint2*>(vr + ((2*q+h) * 32 + m) * 4);
      partial += bflo(vv.x) * u[4*q+0] + bfhi(vv.x) * u[4*q+1]
               + bflo(vv.y) * u[4*q+2] + bfhi(vv.y) * u[4*q+3];
    }
    float logit = partial + __shfl_xor(partial, 32);
    // |logit| small (V squashed): exp safe w/o max-sub; shift-invariant.
    float e = __expf(logit);
    pden += e;
    if (h == 0) eC[(size_t)i * 2048 + n * 32 + m] = e;   // 128B contiguous
  }
  if (h == 0) denP[(size_t)i * 64 + half * 32 + m] = pden;
}

// accum r1/r2: weighted GEMM, c = e/(dp0+dp1). Wave owns (n, i-chunk of 32):
// afrag stream = 32 KB FULLY CONTIGUOUS Wb. No LDS, no barriers.
// grid 1024 x 256 = 4096 waves.
__global__ __launch_bounds__(256) void caps_accum(
    const unsigned short* __restrict__ xb, const unsigned short* __restrict__ Wb,
    const float* __restrict__ eC, const float* __restrict__ denP,
    float* __restrict__ sPart)
{
  const int t = threadIdx.x, w = t >> 6, l = t & 63;
  const int m = l & 31, h = l >> 5;
  const int Wv = blockIdx.x * 4 + w;             // 0..4095
  const int n = Wv & 63, ch = Wv >> 6;
  const int i0 = ch * 32;
  const unsigned short* wrow = Wb + ((size_t)n * IC + i0) * 512 + l * 8;
  const unsigned short* xrow = xb + (size_t)i0 * 512 + l * 8;
  f32x16 sacc = (f32x16)0.0f;
#pragma unroll 4
  for (int ii = 0; ii < 32; ++ii) {
    bf16x8 af = *reinterpret_cast<const bf16x8*>(wrow + (size_t)ii * 512);
    bf16x8 bf = *reinterpret_cast<const bf16x8*>(xrow + (size_t)ii * 512);
    f32x16 u = __builtin_amdgcn_mfma_f32_32x32x16_bf16(
        af, bf, (f32x16)0.0f, 0, 0, 0);
    float e  = eC[(size_t)(i0 + ii) * 2048 + n * 32 + m];
    float dp = denP[(size_t)(i0 + ii) * 64 + m]
             + denP[(size_t)(i0 + ii) * 64 + 32 + m];
    float c = e / dp;
#pragma unroll
    for (int k = 0; k < 16; ++k) sacc[k] += c * u[k];
  }
  float* page = sPart + ((size_t)n * 64 + ch) * 1024;
#pragma unroll
  for (int q = 0; q < 4; ++q) {
    float4 v = make_float4(sacc[4*q], sacc[4*q+1], sacc[4*q+2], sacc[4*q+3]);
    *reinterpret_cast<float4*>(page + ((2*q+h) * 32 + m) * 4) = v;
  }
}

// fused 64-page reduce + squash; emits V (f32), Vb2 (bf16) or out.
// grid 64 (n) x 256 (t = dc*32 + b).
__global__ __launch_bounds__(256) void caps_redsq(
    const float4* __restrict__ sPart, float* __restrict__ V,
    unsigned short* __restrict__ Vb2, float* __restrict__ out, int mode)
{
  const int n = blockIdx.x, t = threadIdx.x;
  const int dc = t >> 5, b = t & 31;
  __shared__ float sq[8][32];
  const float4* base = sPart + (size_t)n * 64 * 256 + t;   // page = 256 float4
  float4 a = make_float4(0.f, 0.f, 0.f, 0.f);
#pragma unroll 8
  for (int ch = 0; ch < 64; ++ch) {
    float4 v = base[(size_t)ch * 256];
    a.x += v.x; a.y += v.y; a.z += v.z; a.w += v.w;
  }
  sq[dc][b] = a.x*a.x + a.y*a.y + a.z*a.z + a.w*a.w;
  __syncthreads();
  float s2 = 0.f;
#pragma unroll
  for (int q = 0; q < 8; ++q) s2 += sq[q][b];
  float scale = s2 / ((1.0f + s2) * sqrtf(s2 + 1e-7f));
  float4 vd = make_float4(a.x*scale, a.y*scale, a.z*scale, a.w*scale);
  const size_t off = ((size_t)b * NC + n) * DD + dc * 4;   // V/out [b][n][d]
  if (mode == 2) {
    *reinterpret_cast<float4*>(out + off) = vd;
  } else {
    float4 nv = vd;
    if (mode == 1) {
      float4 old = *reinterpret_cast<const float4*>(V + off);
      nv.x += old.x; nv.y += old.y; nv.z += old.z; nv.w += old.w;
    }
    *reinterpret_cast<float4*>(V + off) = nv;
    uint2 pb;
    pb.x = pk2(nv.x, nv.y);
    pb.y = pk2(nv.z, nv.w);
    // Vb2[n][dc][b][4] bf16
    *reinterpret_cast<uint2*>(Vb2 + (size_t)n * 1024 + (dc * 32 + b) * 4) = pb;
  }
}

// ============================== fallback: R6 f32 path (ws too small) ========
__global__ void fb_zero(float* __restrict__ s) {
  s[blockIdx.x * 256 + threadIdx.x] = 0.0f;
}
__global__ __launch_bounds__(1024, 4)
void fb_pass(const float* __restrict__ x, const float* __restrict__ W,
             const float* __restrict__ V, float* __restrict__ sOut,
             float* __restrict__ sPart, int r, int usePart)
{
  const int t = threadIdx.x, w = t >> 6, l = t & 63;
  const int n = (w << 2) | (l >> 4);
  const int d0 = (l & 15) << 1;
  const int blk = blockIdx.x, xcd = blk & 7, slot = blk >> 3;
  const int ic = xcd * 8 + (slot >> 3), bq = slot & 7;
  const int i0 = ic * 32, bbase = bq * 4;
  __shared__ float den[2][4];
  __shared__ float Vlds[4 * NC * DD];
  if (r != 0) {
    const float4* src = reinterpret_cast<const float4*>(V + (size_t)bbase * 2048);
    float4* dst = reinterpret_cast<float4*>(Vlds);
    dst[t] = src[t]; dst[t + 1024] = src[t + 1024];
  }
  float acc0[4], acc1[4];
#pragma unroll
  for (int b = 0; b < 4; ++b) { acc0[b] = 0.f; acc1[b] = 0.f; }
  for (int ii = 0; ii < 32; ++ii) {
    const int i = i0 + ii, p = ii & 1;
    const float4* Wp = reinterpret_cast<const float4*>(
        W + (((size_t)n * IC + i) * DD + d0) * JD);
    float4 wr[8];
#pragma unroll
    for (int q = 0; q < 8; ++q) wr[q] = Wp[q];
    if (r == 0) {
#pragma unroll
      for (int bb = 0; bb < 4; ++bb) {
        const float* xp = x + ((size_t)(bbase + bb) * IC + i) * JD;
        float u0 = 0.f, u1 = 0.f;
#pragma unroll
        for (int q = 0; q < 4; ++q) {
          float4 w0 = wr[q], w1 = wr[4 + q];
          float x0 = xp[4*q], x1 = xp[4*q+1], x2 = xp[4*q+2], x3 = xp[4*q+3];
          u0 += w0.x*x0 + w0.y*x1 + w0.z*x2 + w0.w*x3;
          u1 += w1.x*x0 + w1.y*x1 + w1.z*x2 + w1.w*x3;
        }
        acc0[bb] += u0 * 0.015625f; acc1[bb] += u1 * 0.015625f;
      }
    } else {
      if (t < 4) den[p][t] = 0.0f;
      __syncthreads();
      float p0a[4], p1a[4];
#pragma unroll
      for (int bb = 0; bb < 4; ++bb) {
        const float* xp = x + ((size_t)(bbase + bb) * IC + i) * JD;
        float u0 = 0.f, u1 = 0.f;
#pragma unroll
        for (int q = 0; q < 4; ++q) {
          float4 w0 = wr[q], w1 = wr[4 + q];
          float x0 = xp[4*q], x1 = xp[4*q+1], x2 = xp[4*q+2], x3 = xp[4*q+3];
          u0 += w0.x*x0 + w0.y*x1 + w0.z*x2 + w0.w*x3;
          u1 += w1.x*x0 + w1.y*x1 + w1.z*x2 + w1.w*x3;
        }
        const float2 vv = *reinterpret_cast<const float2*>(
            &Vlds[((size_t)bb * NC + n) * DD + d0]);
        float lp = u0 * vv.x + u1 * vv.y;
        float logit = row16_sum(lp);
        float e = __expf(logit);
        p0a[bb] = e * u0; p1a[bb] = e * u1;
        float es = e + __shfl_xor(e, 16);
        es += __shfl_xor(es, 32);
        if (l == 0) atomicAdd(&den[p][bb], es);
      }
      __syncthreads();
#pragma unroll
      for (int bb = 0; bb < 4; ++bb) {
        float rd = 1.0f / den[p][bb];
        acc0[bb] += p0a[bb] * rd; acc1[bb] += p1a[bb] * rd;
      }
    }
  }
  if (usePart) {
#pragma unroll
    for (int bb = 0; bb < 4; ++bb) {
      float2 v2 = make_float2(acc0[bb], acc1[bb]);
      size_t off = (((size_t)(bq * 64 + ic) * 4 + bb) * NC + n) * DD + d0;
      *reinterpret_cast<float2*>(sPart + off) = v2;
    }
  } else {
#pragma unroll
    for (int bb = 0; bb < 4; ++bb) {
      float* sp = sOut + ((size_t)(bbase + bb) * NC + n) * DD + d0;
      atomicAdd(sp, acc0[bb]); atomicAdd(sp + 1, acc1[bb]);
    }
  }
}
__global__ void fb_reduceS(const float4* __restrict__ sPart, float4* __restrict__ s) {
  int q = blockIdx.x * 256 + threadIdx.x;
  int bq = q >> 11, qq = q & 2047;
  float4 sum = make_float4(0.f, 0.f, 0.f, 0.f);
#pragma unroll 8
  for (int p = 0; p < 64; ++p) {
    float4 v = sPart[(size_t)(bq * 64 + p) * 2048 + qq];
    sum.x += v.x; sum.y += v.y; sum.z += v.z; sum.w += v.w;
  }
  s[q] = sum;
}
__global__ void fb_squash(const float* __restrict__ s, float* __restrict__ V,
                          float* __restrict__ out, int mode)
{
  const int t = threadIdx.x;
  const int g = blockIdx.x * 8 + (t >> 5);
  const int d = t & 31;
  float v = s[(size_t)g * DD + d];
  float s2 = v * v;
#pragma unroll
  for (int off = 16; off; off >>= 1) s2 += __shfl_xor(s2, off);
  float scale = s2 / ((1.0f + s2) * sqrtf(s2 + 1e-7f));
  float vd = scale * v;
  if (mode == 2)      out[(size_t)g * DD + d] = vd;
  else if (mode == 0) V[(size_t)g * DD + d] = vd;
  else                V[(size_t)g * DD + d] += vd;
}

// ---------------------------------------------------------------------------
extern "C" void kernel_launch(void* const* d_in, const int* in_sizes, int n_in,
                              void* d_out, int out_size, void* d_ws, size_t ws_size,
                              hipStream_t stream) {
  const float* x = (const float*)d_in[0];
  const float* W = (const float*)d_in[1];
  float* out = (float*)d_out;
  char* ws = (char*)d_ws;
  // Wb 134217728 | xb 2097152 | eC 16777216 | denP 524288 | sPart 16777216
  // V 262144 | Vb2 131072  => 170786816
  const size_t NEED_NEW = 170786816ull;

  if (ws_size >= NEED_NEW) {
    unsigned short* Wb  = (unsigned short*)ws;
    unsigned short* xb  = (unsigned short*)(ws + 134217728);
    float* eC           = (float*)(ws + 136314880);
    float* denP         = (float*)(ws + 153092096);
    float* sPart        = (float*)(ws + 153616384);
    float* V            = (float*)(ws + 170393600);
    unsigned short* Vb2 = (unsigned short*)(ws + 170655744);

    xb_conv<<<512, 256, 0, stream>>>(x, xb);
    caps_conv0<<<1024, 256, 0, stream>>>(xb, W, Wb, sPart);   // conv + round 0
    caps_redsq<<<64, 256, 0, stream>>>((const float4*)sPart, V, Vb2, out, 0);
    for (int r = 1; r < 3; ++r) {
      caps_logits<<<1024, 256, 0, stream>>>(xb, Wb, Vb2, eC, denP);
      caps_accum<<<1024, 256, 0, stream>>>(xb, Wb, eC, denP, sPart);
      caps_redsq<<<64, 256, 0, stream>>>((const float4*)sPart, V, Vb2, out,
                                         r == 2 ? 2 : 1);
    }
  } else {
    float* s     = (float*)ws;
    float* V     = s + 65536;
    float* sPart = V + 65536;
    const size_t need1 = (2ull * 65536 + 512ull * 8192) * 4;
    const int usePart = (ws_size >= need1) ? 1 : 0;
    for (int r = 0; r < 3; ++r) {
      if (!usePart) fb_zero<<<256, 256, 0, stream>>>(s);
      fb_pass<<<512, 1024, 0, stream>>>(x, W, V, s, sPart, r, usePart);
      if (usePart)
        fb_reduceS<<<64, 256, 0, stream>>>((const float4*)sPart, (float4*)s);
      fb_squash<<<256, 256, 0, stream>>>(s, V, out, r == 2 ? 2 : (r == 0 ? 0 : 1));
    }
  }
}

// Round 14
// 242.539 us; speedup vs baseline: 2.0037x; 1.0004x over previous
//
#include <hip/hip_runtime.h>
#include <cstddef>
#include <cstdint>

typedef short  bf16x8 __attribute__((ext_vector_type(8)));
typedef float  f32x16 __attribute__((ext_vector_type(16)));

#define IC 2048
#define JD 16
#define NC 64
#define DD 32

// ---------------------------------------------------------------- helpers ---
__device__ __forceinline__ unsigned f2bf1(float f) {          // RNE f32->bf16
  unsigned u = __float_as_uint(f);
  return (u + 0x7FFFu + ((u >> 16) & 1u)) >> 16;
}
__device__ __forceinline__ unsigned pk2(float lo, float hi) { // 2 bf16 in u32
  return f2bf1(lo) | (f2bf1(hi) << 16);
}
__device__ __forceinline__ float bflo(unsigned v) { return __uint_as_float(v << 16); }
__device__ __forceinline__ float bfhi(unsigned v) { return __uint_as_float(v & 0xFFFF0000u); }

template<int CTRL>
__device__ __forceinline__ float dpp_mov_f(float v) {
  int x = __builtin_amdgcn_mov_dpp(__float_as_int(v), CTRL, 0xf, 0xf, true);
  return __int_as_float(x);
}
__device__ __forceinline__ float row16_sum(float v) {
  v += dpp_mov_f<0x121>(v);
  v += dpp_mov_f<0x122>(v);
  v += dpp_mov_f<0x124>(v);
  v += dpp_mov_f<0x128>(v);
  return v;
}

// ===================================================== streaming MFMA path ==
// Wb fragment-order: row r = n*IC+i (131072 rows x 512 ushort = 1KB).
// Lane l's granule Wb[r*512 + l*8 .. +8] = bf16 W[n][i][d=l&31][j=(l>>5)*8..+8].
// xb: same per-row fragment order for x: row i, lane l -> x[b=l&31][i][j=...].
// Vb2: [n][dc(0..7)][b(0..31)][4] bf16 (dc = d/4) -> contiguous dot loads.
// eC: [i][n][b] f32 raw exp; denP: [i][half(2)][b] f32 partial denominators.

// x -> xb (4 MB -> 2 MB), one granule per thread. grid 512 x 256.
__global__ __launch_bounds__(256) void xb_conv(
    const float* __restrict__ x, unsigned short* __restrict__ xb)
{
  int gid = blockIdx.x * 256 + threadIdx.x;      // 131072
  int i = gid >> 6, l = gid & 63;
  const float* xs = x + ((size_t)(l & 31) * IC + i) * JD + (l >> 5) * 8;
  float4 a = *reinterpret_cast<const float4*>(xs);
  float4 b = *reinterpret_cast<const float4*>(xs + 4);
  uint4 p;
  p.x = pk2(a.x, a.y); p.y = pk2(a.z, a.w);
  p.z = pk2(b.x, b.y); p.w = pk2(b.z, b.w);
  *reinterpret_cast<uint4*>(xb + (size_t)i * 512 + l * 8) = p;
}

// FUSED: W f32 -> Wb bf16 conversion + round-0 accumulation (c = 1/64 exact).
// Wave owns (n, i-chunk of 32): W f32 read CONTIGUOUS (lane l -> row+l*32B),
// Wb store = within-1KB permuted 16B/lane, own MFMA A-frag via 4 ds_bpermute
// pulls from lane src(l) (inverse of the store perm). sacc chained.
// grid 1024 x 256 = 4096 waves. No barriers, no LDS arrays.
__global__ __launch_bounds__(256) void caps_conv0(
    const unsigned short* __restrict__ xb, const float* __restrict__ Wf,
    unsigned short* __restrict__ Wb, float* __restrict__ sPart)
{
  const int t = threadIdx.x, w = t >> 6, l = t & 63;
  const int m = l & 31, h = l >> 5;
  const int Wv = blockIdx.x * 4 + w;             // 0..4095
  const int n = Wv & 63, ch = Wv >> 6;
  const int i0 = ch * 32;
  const int ld   = ((l & 1) << 5) | (l >> 1);
  const int srci = (((l & 31) << 1) | (l >> 5)) << 2;   // byte addr for bperm
  const float* wrow = Wf + ((size_t)n * IC + i0) * 512 + (size_t)l * 8;
  unsigned short* wbrow = Wb + ((size_t)n * IC + i0) * 512 + (size_t)ld * 8;
  const unsigned short* xrow = xb + (size_t)i0 * 512 + l * 8;
  f32x16 sacc = (f32x16)0.0f;
#pragma unroll 4
  for (int ii = 0; ii < 32; ++ii) {
    float4 a = *reinterpret_cast<const float4*>(wrow + (size_t)ii * 512);
    float4 b = *reinterpret_cast<const float4*>(wrow + (size_t)ii * 512 + 4);
    uint4 p;
    p.x = pk2(a.x, a.y); p.y = pk2(a.z, a.w);
    p.z = pk2(b.x, b.y); p.w = pk2(b.z, b.w);
    *reinterpret_cast<uint4*>(wbrow + (size_t)ii * 512) = p;   // frag-order Wb
    uint4 af;                                     // pull my fragment
    af.x = (unsigned)__builtin_amdgcn_ds_bpermute(srci, (int)p.x);
    af.y = (unsigned)__builtin_amdgcn_ds_bpermute(srci, (int)p.y);
    af.z = (unsigned)__builtin_amdgcn_ds_bpermute(srci, (int)p.z);
    af.w = (unsigned)__builtin_amdgcn_ds_bpermute(srci, (int)p.w);
    bf16x8 bf = *reinterpret_cast<const bf16x8*>(xrow + (size_t)ii * 512);
    sacc = __builtin_amdgcn_mfma_f32_32x32x16_bf16(
        *reinterpret_cast<bf16x8*>(&af), bf, sacc, 0, 0, 0);
  }
  float* page = sPart + ((size_t)n * 64 + ch) * 1024;   // [dc][b][4] = 4 KB
#pragma unroll
  for (int q = 0; q < 4; ++q) {
    float4 v = make_float4(sacc[4*q] * 0.015625f, sacc[4*q+1] * 0.015625f,
                           sacc[4*q+2] * 0.015625f, sacc[4*q+3] * 0.015625f);
    *reinterpret_cast<float4*>(page + ((2*q+h) * 32 + m) * 4) = v;
  }
}

// logits (r>=1): wave owns (i, n-half of 32). Barrier-free stream of 32
// contiguous 1KB afrag rows; stores RAW e and per-half den partial.
// grid 1024 x 256 (4 waves) = 4096 waves.
__global__ __launch_bounds__(256) void caps_logits(
    const unsigned short* __restrict__ xb, const unsigned short* __restrict__ Wb,
    const unsigned short* __restrict__ Vb2, float* __restrict__ eC,
    float* __restrict__ denP)
{
  const int t = threadIdx.x, w = t >> 6, l = t & 63;
  const int m = l & 31, h = l >> 5;
  const int Wv = blockIdx.x * 4 + w;             // 0..4095
  const int i = Wv >> 1, half = Wv & 1;
  const int n0 = half * 32;
  bf16x8 bfrag = *reinterpret_cast<const bf16x8*>(xb + (size_t)i * 512 + l * 8);
  float pden = 0.f;
#pragma unroll 2
  for (int nn = 0; nn < 32; ++nn) {
    const int n = n0 + nn;
    bf16x8 af = *reinterpret_cast<const bf16x8*>(
        Wb + ((size_t)n * IC + i) * 512 + l * 8);        // contiguous 1KB/wave
    f32x16 u = __builtin_amdgcn_mfma_f32_32x32x16_bf16(
        af, bfrag, (f32x16)0.0f, 0, 0, 0);
    float partial = 0.f;
    const unsigned short* vr = Vb2 + (size_t)n * 1024;
#pragma unroll
    for (int q = 0; q < 4; ++q) {                // contiguous 256B per chunk
      uint2 vv = *reinterpret_cast<const uint2*>(vr + ((2*q+h) * 32 + m) * 4);
      partial += bflo(vv.x) * u[4*q+0] + bfhi(vv.x) * u[4*q+1]
               + bflo(vv.y) * u[4*q+2] + bfhi(vv.y) * u[4*q+3];
    }
    float logit = partial + __shfl_xor(partial, 32);
    // |logit| small (V squashed): exp safe w/o max-sub; shift-invariant.
    float e = __expf(logit);
    pden += e;
    if (h == 0) eC[(size_t)i * 2048 + n * 32 + m] = e;   // 128B contiguous
  }
  if (h == 0) denP[(size_t)i * 64 + half * 32 + m] = pden;
}

// accum r1/r2: weighted GEMM, c = e/(dp0+dp1). Wave owns (n, i-chunk of 32):
// afrag stream = 32 KB FULLY CONTIGUOUS Wb. No LDS, no barriers.
// grid 1024 x 256 = 4096 waves.
__global__ __launch_bounds__(256) void caps_accum(
    const unsigned short* __restrict__ xb, const unsigned short* __restrict__ Wb,
    const float* __restrict__ eC, const float* __restrict__ denP,
    float* __restrict__ sPart)
{
  const int t = threadIdx.x, w = t >> 6, l = t & 63;
  const int m = l & 31, h = l >> 5;
  const int Wv = blockIdx.x * 4 + w;             // 0..4095
  const int n = Wv & 63, ch = Wv >> 6;
  const int i0 = ch * 32;
  const unsigned short* wrow = Wb + ((size_t)n * IC + i0) * 512 + l * 8;
  const unsigned short* xrow = xb + (size_t)i0 * 512 + l * 8;
  f32x16 sacc = (f32x16)0.0f;
#pragma unroll 4
  for (int ii = 0; ii < 32; ++ii) {
    bf16x8 af = *reinterpret_cast<const bf16x8*>(wrow + (size_t)ii * 512);
    bf16x8 bf = *reinterpret_cast<const bf16x8*>(xrow + (size_t)ii * 512);
    f32x16 u = __builtin_amdgcn_mfma_f32_32x32x16_bf16(
        af, bf, (f32x16)0.0f, 0, 0, 0);
    float e  = eC[(size_t)(i0 + ii) * 2048 + n * 32 + m];
    float dp = denP[(size_t)(i0 + ii) * 64 + m]
             + denP[(size_t)(i0 + ii) * 64 + 32 + m];
    float c = e / dp;
#pragma unroll
    for (int k = 0; k < 16; ++k) sacc[k] += c * u[k];
  }
  float* page = sPart + ((size_t)n * 64 + ch) * 1024;
#pragma unroll
  for (int q = 0; q < 4; ++q) {
    float4 v = make_float4(sacc[4*q], sacc[4*q+1], sacc[4*q+2], sacc[4*q+3]);
    *reinterpret_cast<float4*>(page + ((2*q+h) * 32 + m) * 4) = v;
  }
}

// fused 64-page reduce + squash; emits V (f32), Vb2 (bf16) or out.
// RE-GRIDDED (R14): 256 blocks (n x b-octet) x 64 thr -> 1 block/CU, full-BW
// sPart stream; s2 reduce over dc = in-wave shfl_xor (no LDS, no barrier).
__global__ __launch_bounds__(64) void caps_redsq(
    const float4* __restrict__ sPart, float* __restrict__ V,
    unsigned short* __restrict__ Vb2, float* __restrict__ out, int mode)
{
  const int n = blockIdx.x >> 2, bq = blockIdx.x & 3;
  const int t = threadIdx.x;               // 64 = dc(8) x b8(8)
  const int dc = t >> 3, b8 = t & 7;
  const int b = bq * 8 + b8;
  const float4* base = sPart + (size_t)n * 64 * 256 + dc * 32 + b;
  float4 a = make_float4(0.f, 0.f, 0.f, 0.f);
#pragma unroll 8
  for (int ch = 0; ch < 64; ++ch) {
    float4 v = base[(size_t)ch * 256];
    a.x += v.x; a.y += v.y; a.z += v.z; a.w += v.w;
  }
  float s2 = a.x*a.x + a.y*a.y + a.z*a.z + a.w*a.w;
  // sum over the 8 dc lanes sharing this b (t strides of 8)
  s2 += __shfl_xor(s2, 8);
  s2 += __shfl_xor(s2, 16);
  s2 += __shfl_xor(s2, 32);
  float scale = s2 / ((1.0f + s2) * sqrtf(s2 + 1e-7f));
  float4 vd = make_float4(a.x*scale, a.y*scale, a.z*scale, a.w*scale);
  const size_t off = ((size_t)b * NC + n) * DD + dc * 4;   // V/out [b][n][d]
  if (mode == 2) {
    *reinterpret_cast<float4*>(out + off) = vd;
  } else {
    float4 nv = vd;
    if (mode == 1) {
      float4 old = *reinterpret_cast<const float4*>(V + off);
      nv.x += old.x; nv.y += old.y; nv.z += old.z; nv.w += old.w;
    }
    *reinterpret_cast<float4*>(V + off) = nv;
    uint2 pb;
    pb.x = pk2(nv.x, nv.y);
    pb.y = pk2(nv.z, nv.w);
    // Vb2[n][dc][b][4] bf16
    *reinterpret_cast<uint2*>(Vb2 + (size_t)n * 1024 + (dc * 32 + b) * 4) = pb;
  }
}

// ============================== fallback: R6 f32 path (ws too small) ========
__global__ void fb_zero(float* __restrict__ s) {
  s[blockIdx.x * 256 + threadIdx.x] = 0.0f;
}
__global__ __launch_bounds__(1024, 4)
void fb_pass(const float* __restrict__ x, const float* __restrict__ W,
             const float* __restrict__ V, float* __restrict__ sOut,
             float* __restrict__ sPart, int r, int usePart)
{
  const int t = threadIdx.x, w = t >> 6, l = t & 63;
  const int n = (w << 2) | (l >> 4);
  const int d0 = (l & 15) << 1;
  const int blk = blockIdx.x, xcd = blk & 7, slot = blk >> 3;
  const int ic = xcd * 8 + (slot >> 3), bq = slot & 7;
  const int i0 = ic * 32, bbase = bq * 4;
  __shared__ float den[2][4];
  __shared__ float Vlds[4 * NC * DD];
  if (r != 0) {
    const float4* src = reinterpret_cast<const float4*>(V + (size_t)bbase * 2048);
    float4* dst = reinterpret_cast<float4*>(Vlds);
    dst[t] = src[t]; dst[t + 1024] = src[t + 1024];
  }
  float acc0[4], acc1[4];
#pragma unroll
  for (int b = 0; b < 4; ++b) { acc0[b] = 0.f; acc1[b] = 0.f; }
  for (int ii = 0; ii < 32; ++ii) {
    const int i = i0 + ii, p = ii & 1;
    const float4* Wp = reinterpret_cast<const float4*>(
        W + (((size_t)n * IC + i) * DD + d0) * JD);
    float4 wr[8];
#pragma unroll
    for (int q = 0; q < 8; ++q) wr[q] = Wp[q];
    if (r == 0) {
#pragma unroll
      for (int bb = 0; bb < 4; ++bb) {
        const float* xp = x + ((size_t)(bbase + bb) * IC + i) * JD;
        float u0 = 0.f, u1 = 0.f;
#pragma unroll
        for (int q = 0; q < 4; ++q) {
          float4 w0 = wr[q], w1 = wr[4 + q];
          float x0 = xp[4*q], x1 = xp[4*q+1], x2 = xp[4*q+2], x3 = xp[4*q+3];
          u0 += w0.x*x0 + w0.y*x1 + w0.z*x2 + w0.w*x3;
          u1 += w1.x*x0 + w1.y*x1 + w1.z*x2 + w1.w*x3;
        }
        acc0[bb] += u0 * 0.015625f; acc1[bb] += u1 * 0.015625f;
      }
    } else {
      if (t < 4) den[p][t] = 0.0f;
      __syncthreads();
      float p0a[4], p1a[4];
#pragma unroll
      for (int bb = 0; bb < 4; ++bb) {
        const float* xp = x + ((size_t)(bbase + bb) * IC + i) * JD;
        float u0 = 0.f, u1 = 0.f;
#pragma unroll
        for (int q = 0; q < 4; ++q) {
          float4 w0 = wr[q], w1 = wr[4 + q];
          float x0 = xp[4*q], x1 = xp[4*q+1], x2 = xp[4*q+2], x3 = xp[4*q+3];
          u0 += w0.x*x0 + w0.y*x1 + w0.z*x2 + w0.w*x3;
          u1 += w1.x*x0 + w1.y*x1 + w1.z*x2 + w1.w*x3;
        }
        const float2 vv = *reinterpret_cast<const float2*>(
            &Vlds[((size_t)bb * NC + n) * DD + d0]);
        float lp = u0 * vv.x + u1 * vv.y;
        float logit = row16_sum(lp);
        float e = __expf(logit);
        p0a[bb] = e * u0; p1a[bb] = e * u1;
        float es = e + __shfl_xor(e, 16);
        es += __shfl_xor(es, 32);
        if (l == 0) atomicAdd(&den[p][bb], es);
      }
      __syncthreads();
#pragma unroll
      for (int bb = 0; bb < 4; ++bb) {
        float rd = 1.0f / den[p][bb];
        acc0[bb] += p0a[bb] * rd; acc1[bb] += p1a[bb] * rd;
      }
    }
  }
  if (usePart) {
#pragma unroll
    for (int bb = 0; bb < 4; ++bb) {
      float2 v2 = make_float2(acc0[bb], acc1[bb]);
      size_t off = (((size_t)(bq * 64 + ic) * 4 + bb) * NC + n) * DD + d0;
      *reinterpret_cast<float2*>(sPart + off) = v2;
    }
  } else {
#pragma unroll
    for (int bb = 0; bb < 4; ++bb) {
      float* sp = sOut + ((size_t)(bbase + bb) * NC + n) * DD + d0;
      atomicAdd(sp, acc0[bb]); atomicAdd(sp + 1, acc1[bb]);
    }
  }
}
__global__ void fb_reduceS(const float4* __restrict__ sPart, float4* __restrict__ s) {
  int q = blockIdx.x * 256 + threadIdx.x;
  int bq = q >> 11, qq = q & 2047;
  float4 sum = make_float4(0.f, 0.f, 0.f, 0.f);
#pragma unroll 8
  for (int p = 0; p < 64; ++p) {
    float4 v = sPart[(size_t)(bq * 64 + p) * 2048 + qq];
    sum.x += v.x; sum.y += v.y; sum.z += v.z; sum.w += v.w;
  }
  s[q] = sum;
}
__global__ void fb_squash(const float* __restrict__ s, float* __restrict__ V,
                          float* __restrict__ out, int mode)
{
  const int t = threadIdx.x;
  const int g = blockIdx.x * 8 + (t >> 5);
  const int d = t & 31;
  float v = s[(size_t)g * DD + d];
  float s2 = v * v;
#pragma unroll
  for (int off = 16; off; off >>= 1) s2 += __shfl_xor(s2, off);
  float scale = s2 / ((1.0f + s2) * sqrtf(s2 + 1e-7f));
  float vd = scale * v;
  if (mode == 2)      out[(size_t)g * DD + d] = vd;
  else if (mode == 0) V[(size_t)g * DD + d] = vd;
  else                V[(size_t)g * DD + d] += vd;
}

// ---------------------------------------------------------------------------
extern "C" void kernel_launch(void* const* d_in, const int* in_sizes, int n_in,
                              void* d_out, int out_size, void* d_ws, size_t ws_size,
                              hipStream_t stream) {
  const float* x = (const float*)d_in[0];
  const float* W = (const float*)d_in[1];
  float* out = (float*)d_out;
  char* ws = (char*)d_ws;
  // Wb 134217728 | xb 2097152 | eC 16777216 | denP 524288 | sPart 16777216
  // V 262144 | Vb2 131072  => 170786816
  const size_t NEED_NEW = 170786816ull;

  if (ws_size >= NEED_NEW) {
    unsigned short* Wb  = (unsigned short*)ws;
    unsigned short* xb  = (unsigned short*)(ws + 134217728);
    float* eC           = (float*)(ws + 136314880);
    float* denP         = (float*)(ws + 153092096);
    float* sPart        = (float*)(ws + 153616384);
    float* V            = (float*)(ws + 170393600);
    unsigned short* Vb2 = (unsigned short*)(ws + 170655744);

    xb_conv<<<512, 256, 0, stream>>>(x, xb);
    caps_conv0<<<1024, 256, 0, stream>>>(xb, W, Wb, sPart);   // conv + round 0
    caps_redsq<<<256, 64, 0, stream>>>((const float4*)sPart, V, Vb2, out, 0);
    for (int r = 1; r < 3; ++r) {
      caps_logits<<<1024, 256, 0, stream>>>(xb, Wb, Vb2, eC, denP);
      caps_accum<<<1024, 256, 0, stream>>>(xb, Wb, eC, denP, sPart);
      caps_redsq<<<256, 64, 0, stream>>>((const float4*)sPart, V, Vb2, out,
                                         r == 2 ? 2 : 1);
    }
  } else {
    float* s     = (float*)ws;
    float* V     = s + 65536;
    float* sPart = V + 65536;
    const size_t need1 = (2ull * 65536 + 512ull * 8192) * 4;
    const int usePart = (ws_size >= need1) ? 1 : 0;
    for (int r = 0; r < 3; ++r) {
      if (!usePart) fb_zero<<<256, 256, 0, stream>>>(s);
      fb_pass<<<512, 1024, 0, stream>>>(x, W, V, s, sPart, r, usePart);
      if (usePart)
        fb_reduceS<<<64, 256, 0, stream>>>((const float4*)sPart, (float4*)s);
      fb_squash<<<256, 256, 0, stream>>>(s, V, out, r == 2 ? 2 : (r == 0 ? 0 : 1));
    }
  }
}

// Round 15
// 229.315 us; speedup vs baseline: 2.1192x; 1.0577x over previous
//
#include <hip/hip_runtime.h>
#include <cstddef>
#include <cstdint>

typedef short  bf16x8 __attribute__((ext_vector_type(8)));
typedef float  f32x16 __attribute__((ext_vector_type(16)));

#define IC 2048
#define JD 16
#define NC 64
#define DD 32

// ---------------------------------------------------------------- helpers ---
__device__ __forceinline__ unsigned f2bf1(float f) {          // RNE f32->bf16
  unsigned u = __float_as_uint(f);
  return (u + 0x7FFFu + ((u >> 16) & 1u)) >> 16;
}
__device__ __forceinline__ unsigned pk2(float lo, float hi) { // 2 bf16 in u32
  return f2bf1(lo) | (f2bf1(hi) << 16);
}
__device__ __forceinline__ float bflo(unsigned v) { return __uint_as_float(v << 16); }
__device__ __forceinline__ float bfhi(unsigned v) { return __uint_as_float(v & 0xFFFF0000u); }

template<int CTRL>
__device__ __forceinline__ float dpp_mov_f(float v) {
  int x = __builtin_amdgcn_mov_dpp(__float_as_int(v), CTRL, 0xf, 0xf, true);
  return __int_as_float(x);
}
__device__ __forceinline__ float row16_sum(float v) {
  v += dpp_mov_f<0x121>(v);
  v += dpp_mov_f<0x122>(v);
  v += dpp_mov_f<0x124>(v);
  v += dpp_mov_f<0x128>(v);
  return v;
}

// ===================================================== streaming MFMA path ==
// Wb fragment-order: row r = n*IC+i (131072 rows x 512 ushort = 1KB).
// Lane l's granule Wb[r*512 + l*8 .. +8] = bf16 W[n][i][d=l&31][j=(l>>5)*8..+8].
// xb: same per-row fragment order for x: row i, lane l -> x[b=l&31][i][j=...].
// Vb2: [n][dc(0..7)][b(0..31)][4] bf16 (dc = d/4) -> contiguous dot loads.
// denP: [i][half(2)][b] f32 partial softmax denominators. (eC dropped in R15:
// accum recomputes e from its own u with the identical FMA sequence.)

// x -> xb (4 MB -> 2 MB), one granule per thread. grid 512 x 256.
__global__ __launch_bounds__(256) void xb_conv(
    const float* __restrict__ x, unsigned short* __restrict__ xb)
{
  int gid = blockIdx.x * 256 + threadIdx.x;      // 131072
  int i = gid >> 6, l = gid & 63;
  const float* xs = x + ((size_t)(l & 31) * IC + i) * JD + (l >> 5) * 8;
  float4 a = *reinterpret_cast<const float4*>(xs);
  float4 b = *reinterpret_cast<const float4*>(xs + 4);
  uint4 p;
  p.x = pk2(a.x, a.y); p.y = pk2(a.z, a.w);
  p.z = pk2(b.x, b.y); p.w = pk2(b.z, b.w);
  *reinterpret_cast<uint4*>(xb + (size_t)i * 512 + l * 8) = p;
}

// FUSED: W f32 -> Wb bf16 conversion + round-0 accumulation (c = 1/64 exact).
// Wave owns (n, i-chunk of 32): W f32 read CONTIGUOUS (lane l -> row+l*32B),
// Wb store = within-1KB permuted 16B/lane, own MFMA A-frag via 4 ds_bpermute
// pulls from lane src(l) (inverse of the store perm). sacc chained.
// grid 1024 x 256 = 4096 waves. No barriers, no LDS arrays.
__global__ __launch_bounds__(256) void caps_conv0(
    const unsigned short* __restrict__ xb, const float* __restrict__ Wf,
    unsigned short* __restrict__ Wb, float* __restrict__ sPart)
{
  const int t = threadIdx.x, w = t >> 6, l = t & 63;
  const int m = l & 31, h = l >> 5;
  const int Wv = blockIdx.x * 4 + w;             // 0..4095
  const int n = Wv & 63, ch = Wv >> 6;
  const int i0 = ch * 32;
  const int ld   = ((l & 1) << 5) | (l >> 1);
  const int srci = (((l & 31) << 1) | (l >> 5)) << 2;   // byte addr for bperm
  const float* wrow = Wf + ((size_t)n * IC + i0) * 512 + (size_t)l * 8;
  unsigned short* wbrow = Wb + ((size_t)n * IC + i0) * 512 + (size_t)ld * 8;
  const unsigned short* xrow = xb + (size_t)i0 * 512 + l * 8;
  f32x16 sacc = (f32x16)0.0f;
#pragma unroll 4
  for (int ii = 0; ii < 32; ++ii) {
    float4 a = *reinterpret_cast<const float4*>(wrow + (size_t)ii * 512);
    float4 b = *reinterpret_cast<const float4*>(wrow + (size_t)ii * 512 + 4);
    uint4 p;
    p.x = pk2(a.x, a.y); p.y = pk2(a.z, a.w);
    p.z = pk2(b.x, b.y); p.w = pk2(b.z, b.w);
    *reinterpret_cast<uint4*>(wbrow + (size_t)ii * 512) = p;   // frag-order Wb
    uint4 af;                                     // pull my fragment
    af.x = (unsigned)__builtin_amdgcn_ds_bpermute(srci, (int)p.x);
    af.y = (unsigned)__builtin_amdgcn_ds_bpermute(srci, (int)p.y);
    af.z = (unsigned)__builtin_amdgcn_ds_bpermute(srci, (int)p.z);
    af.w = (unsigned)__builtin_amdgcn_ds_bpermute(srci, (int)p.w);
    bf16x8 bf = *reinterpret_cast<const bf16x8*>(xrow + (size_t)ii * 512);
    sacc = __builtin_amdgcn_mfma_f32_32x32x16_bf16(
        *reinterpret_cast<bf16x8*>(&af), bf, sacc, 0, 0, 0);
  }
  float* page = sPart + ((size_t)n * 64 + ch) * 1024;   // [dc][b][4] = 4 KB
#pragma unroll
  for (int q = 0; q < 4; ++q) {
    float4 v = make_float4(sacc[4*q] * 0.015625f, sacc[4*q+1] * 0.015625f,
                           sacc[4*q+2] * 0.015625f, sacc[4*q+3] * 0.015625f);
    *reinterpret_cast<float4*>(page + ((2*q+h) * 32 + m) * 4) = v;
  }
}

// den pass (r>=1): wave owns (i, n-half of 32). Barrier-free stream of 32
// contiguous 1KB afrag rows; stores ONLY the per-half den partial (R15).
// grid 1024 x 256 (4 waves) = 4096 waves.
__global__ __launch_bounds__(256) void caps_den(
    const unsigned short* __restrict__ xb, const unsigned short* __restrict__ Wb,
    const unsigned short* __restrict__ Vb2, float* __restrict__ denP)
{
  const int t = threadIdx.x, w = t >> 6, l = t & 63;
  const int m = l & 31, h = l >> 5;
  const int Wv = blockIdx.x * 4 + w;             // 0..4095
  const int i = Wv >> 1, half = Wv & 1;
  const int n0 = half * 32;
  bf16x8 bfrag = *reinterpret_cast<const bf16x8*>(xb + (size_t)i * 512 + l * 8);
  float pden = 0.f;
#pragma unroll 2
  for (int nn = 0; nn < 32; ++nn) {
    const int n = n0 + nn;
    bf16x8 af = *reinterpret_cast<const bf16x8*>(
        Wb + ((size_t)n * IC + i) * 512 + l * 8);        // contiguous 1KB/wave
    f32x16 u = __builtin_amdgcn_mfma_f32_32x32x16_bf16(
        af, bfrag, (f32x16)0.0f, 0, 0, 0);
    float partial = 0.f;
    const unsigned short* vr = Vb2 + (size_t)n * 1024;
#pragma unroll
    for (int q = 0; q < 4; ++q) {                // contiguous 256B per chunk
      uint2 vv = *reinterpret_cast<const uint2*>(vr + ((2*q+h) * 32 + m) * 4);
      partial += bflo(vv.x) * u[4*q+0] + bfhi(vv.x) * u[4*q+1]
               + bflo(vv.y) * u[4*q+2] + bfhi(vv.y) * u[4*q+3];
    }
    float logit = partial + __shfl_xor(partial, 32);
    // |logit| small (V squashed): exp safe w/o max-sub; shift-invariant.
    pden += __expf(logit);
  }
  if (h == 0) denP[(size_t)i * 64 + half * 32 + m] = pden;
}

// accum r1/r2: weighted GEMM; e recomputed LOCALLY from u (identical FMA
// order as caps_den -> bit-identical c). Wave owns (n, i-chunk of 32):
// afrag stream = 32 KB FULLY CONTIGUOUS Wb. No LDS, no barriers.
// grid 1024 x 256 = 4096 waves.
__global__ __launch_bounds__(256) void caps_accum(
    const unsigned short* __restrict__ xb, const unsigned short* __restrict__ Wb,
    const unsigned short* __restrict__ Vb2, const float* __restrict__ denP,
    float* __restrict__ sPart)
{
  const int t = threadIdx.x, w = t >> 6, l = t & 63;
  const int m = l & 31, h = l >> 5;
  const int Wv = blockIdx.x * 4 + w;             // 0..4095
  const int n = Wv & 63, ch = Wv >> 6;
  const int i0 = ch * 32;
  const unsigned short* wrow = Wb + ((size_t)n * IC + i0) * 512 + l * 8;
  const unsigned short* xrow = xb + (size_t)i0 * 512 + l * 8;
  const unsigned short* vr = Vb2 + (size_t)n * 1024;
  f32x16 sacc = (f32x16)0.0f;
#pragma unroll 4
  for (int ii = 0; ii < 32; ++ii) {
    bf16x8 af = *reinterpret_cast<const bf16x8*>(wrow + (size_t)ii * 512);
    bf16x8 bf = *reinterpret_cast<const bf16x8*>(xrow + (size_t)ii * 512);
    f32x16 u = __builtin_amdgcn_mfma_f32_32x32x16_bf16(
        af, bf, (f32x16)0.0f, 0, 0, 0);
    // recompute e with the SAME dot sequence as caps_den (lane m = b)
    float partial = 0.f;
#pragma unroll
    for (int q = 0; q < 4; ++q) {
      uint2 vv = *reinterpret_cast<const uint2*>(vr + ((2*q+h) * 32 + m) * 4);
      partial += bflo(vv.x) * u[4*q+0] + bfhi(vv.x) * u[4*q+1]
               + bflo(vv.y) * u[4*q+2] + bfhi(vv.y) * u[4*q+3];
    }
    float logit = partial + __shfl_xor(partial, 32);
    float e = __expf(logit);
    float dp = denP[(size_t)(i0 + ii) * 64 + m]
             + denP[(size_t)(i0 + ii) * 64 + 32 + m];
    float c = e / dp;
#pragma unroll
    for (int k = 0; k < 16; ++k) sacc[k] += c * u[k];
  }
  float* page = sPart + ((size_t)n * 64 + ch) * 1024;
#pragma unroll
  for (int q = 0; q < 4; ++q) {
    float4 v = make_float4(sacc[4*q], sacc[4*q+1], sacc[4*q+2], sacc[4*q+3]);
    *reinterpret_cast<float4*>(page + ((2*q+h) * 32 + m) * 4) = v;
  }
}

// fused 64-page reduce + squash; emits V (f32), Vb2 (bf16) or out.
// 256 blocks (n x b-octet) x 64 thr; s2 reduce over dc via shfl_xor.
__global__ __launch_bounds__(64) void caps_redsq(
    const float4* __restrict__ sPart, float* __restrict__ V,
    unsigned short* __restrict__ Vb2, float* __restrict__ out, int mode)
{
  const int n = blockIdx.x >> 2, bq = blockIdx.x & 3;
  const int t = threadIdx.x;               // 64 = dc(8) x b8(8)
  const int dc = t >> 3, b8 = t & 7;
  const int b = bq * 8 + b8;
  const float4* base = sPart + (size_t)n * 64 * 256 + dc * 32 + b;
  float4 a = make_float4(0.f, 0.f, 0.f, 0.f);
#pragma unroll 8
  for (int ch = 0; ch < 64; ++ch) {
    float4 v = base[(size_t)ch * 256];
    a.x += v.x; a.y += v.y; a.z += v.z; a.w += v.w;
  }
  float s2 = a.x*a.x + a.y*a.y + a.z*a.z + a.w*a.w;
  s2 += __shfl_xor(s2, 8);
  s2 += __shfl_xor(s2, 16);
  s2 += __shfl_xor(s2, 32);
  float scale = s2 / ((1.0f + s2) * sqrtf(s2 + 1e-7f));
  float4 vd = make_float4(a.x*scale, a.y*scale, a.z*scale, a.w*scale);
  const size_t off = ((size_t)b * NC + n) * DD + dc * 4;   // V/out [b][n][d]
  if (mode == 2) {
    *reinterpret_cast<float4*>(out + off) = vd;
  } else {
    float4 nv = vd;
    if (mode == 1) {
      float4 old = *reinterpret_cast<const float4*>(V + off);
      nv.x += old.x; nv.y += old.y; nv.z += old.z; nv.w += old.w;
    }
    *reinterpret_cast<float4*>(V + off) = nv;
    uint2 pb;
    pb.x = pk2(nv.x, nv.y);
    pb.y = pk2(nv.z, nv.w);
    *reinterpret_cast<uint2*>(Vb2 + (size_t)n * 1024 + (dc * 32 + b) * 4) = pb;
  }
}

// ============================== fallback: R6 f32 path (ws too small) ========
__global__ void fb_zero(float* __restrict__ s) {
  s[blockIdx.x * 256 + threadIdx.x] = 0.0f;
}
__global__ __launch_bounds__(1024, 4)
void fb_pass(const float* __restrict__ x, const float* __restrict__ W,
             const float* __restrict__ V, float* __restrict__ sOut,
             float* __restrict__ sPart, int r, int usePart)
{
  const int t = threadIdx.x, w = t >> 6, l = t & 63;
  const int n = (w << 2) | (l >> 4);
  const int d0 = (l & 15) << 1;
  const int blk = blockIdx.x, xcd = blk & 7, slot = blk >> 3;
  const int ic = xcd * 8 + (slot >> 3), bq = slot & 7;
  const int i0 = ic * 32, bbase = bq * 4;
  __shared__ float den[2][4];
  __shared__ float Vlds[4 * NC * DD];
  if (r != 0) {
    const float4* src = reinterpret_cast<const float4*>(V + (size_t)bbase * 2048);
    float4* dst = reinterpret_cast<float4*>(Vlds);
    dst[t] = src[t]; dst[t + 1024] = src[t + 1024];
  }
  float acc0[4], acc1[4];
#pragma unroll
  for (int b = 0; b < 4; ++b) { acc0[b] = 0.f; acc1[b] = 0.f; }
  for (int ii = 0; ii < 32; ++ii) {
    const int i = i0 + ii, p = ii & 1;
    const float4* Wp = reinterpret_cast<const float4*>(
        W + (((size_t)n * IC + i) * DD + d0) * JD);
    float4 wr[8];
#pragma unroll
    for (int q = 0; q < 8; ++q) wr[q] = Wp[q];
    if (r == 0) {
#pragma unroll
      for (int bb = 0; bb < 4; ++bb) {
        const float* xp = x + ((size_t)(bbase + bb) * IC + i) * JD;
        float u0 = 0.f, u1 = 0.f;
#pragma unroll
        for (int q = 0; q < 4; ++q) {
          float4 w0 = wr[q], w1 = wr[4 + q];
          float x0 = xp[4*q], x1 = xp[4*q+1], x2 = xp[4*q+2], x3 = xp[4*q+3];
          u0 += w0.x*x0 + w0.y*x1 + w0.z*x2 + w0.w*x3;
          u1 += w1.x*x0 + w1.y*x1 + w1.z*x2 + w1.w*x3;
        }
        acc0[bb] += u0 * 0.015625f; acc1[bb] += u1 * 0.015625f;
      }
    } else {
      if (t < 4) den[p][t] = 0.0f;
      __syncthreads();
      float p0a[4], p1a[4];
#pragma unroll
      for (int bb = 0; bb < 4; ++bb) {
        const float* xp = x + ((size_t)(bbase + bb) * IC + i) * JD;
        float u0 = 0.f, u1 = 0.f;
#pragma unroll
        for (int q = 0; q < 4; ++q) {
          float4 w0 = wr[q], w1 = wr[4 + q];
          float x0 = xp[4*q], x1 = xp[4*q+1], x2 = xp[4*q+2], x3 = xp[4*q+3];
          u0 += w0.x*x0 + w0.y*x1 + w0.z*x2 + w0.w*x3;
          u1 += w1.x*x0 + w1.y*x1 + w1.z*x2 + w1.w*x3;
        }
        const float2 vv = *reinterpret_cast<const float2*>(
            &Vlds[((size_t)bb * NC + n) * DD + d0]);
        float lp = u0 * vv.x + u1 * vv.y;
        float logit = row16_sum(lp);
        float e = __expf(logit);
        p0a[bb] = e * u0; p1a[bb] = e * u1;
        float es = e + __shfl_xor(e, 16);
        es += __shfl_xor(es, 32);
        if (l == 0) atomicAdd(&den[p][bb], es);
      }
      __syncthreads();
#pragma unroll
      for (int bb = 0; bb < 4; ++bb) {
        float rd = 1.0f / den[p][bb];
        acc0[bb] += p0a[bb] * rd; acc1[bb] += p1a[bb] * rd;
      }
    }
  }
  if (usePart) {
#pragma unroll
    for (int bb = 0; bb < 4; ++bb) {
      float2 v2 = make_float2(acc0[bb], acc1[bb]);
      size_t off = (((size_t)(bq * 64 + ic) * 4 + bb) * NC + n) * DD + d0;
      *reinterpret_cast<float2*>(sPart + off) = v2;
    }
  } else {
#pragma unroll
    for (int bb = 0; bb < 4; ++bb) {
      float* sp = sOut + ((size_t)(bbase + bb) * NC + n) * DD + d0;
      atomicAdd(sp, acc0[bb]); atomicAdd(sp + 1, acc1[bb]);
    }
  }
}
__global__ void fb_reduceS(const float4* __restrict__ sPart, float4* __restrict__ s) {
  int q = blockIdx.x * 256 + threadIdx.x;
  int bq = q >> 11, qq = q & 2047;
  float4 sum = make_float4(0.f, 0.f, 0.f, 0.f);
#pragma unroll 8
  for (int p = 0; p < 64; ++p) {
    float4 v = sPart[(size_t)(bq * 64 + p) * 2048 + qq];
    sum.x += v.x; sum.y += v.y; sum.z += v.z; sum.w += v.w;
  }
  s[q] = sum;
}
__global__ void fb_squash(const float* __restrict__ s, float* __restrict__ V,
                          float* __restrict__ out, int mode)
{
  const int t = threadIdx.x;
  const int g = blockIdx.x * 8 + (t >> 5);
  const int d = t & 31;
  float v = s[(size_t)g * DD + d];
  float s2 = v * v;
#pragma unroll
  for (int off = 16; off; off >>= 1) s2 += __shfl_xor(s2, off);
  float scale = s2 / ((1.0f + s2) * sqrtf(s2 + 1e-7f));
  float vd = scale * v;
  if (mode == 2)      out[(size_t)g * DD + d] = vd;
  else if (mode == 0) V[(size_t)g * DD + d] = vd;
  else                V[(size_t)g * DD + d] += vd;
}

// ---------------------------------------------------------------------------
extern "C" void kernel_launch(void* const* d_in, const int* in_sizes, int n_in,
                              void* d_out, int out_size, void* d_ws, size_t ws_size,
                              hipStream_t stream) {
  const float* x = (const float*)d_in[0];
  const float* W = (const float*)d_in[1];
  float* out = (float*)d_out;
  char* ws = (char*)d_ws;
  // Wb 134217728 | xb 2097152 | denP 524288 | sPart 16777216 | V 262144
  // Vb2 131072  => 154009600
  const size_t NEED_NEW = 154009600ull;

  if (ws_size >= NEED_NEW) {
    unsigned short* Wb  = (unsigned short*)ws;
    unsigned short* xb  = (unsigned short*)(ws + 134217728);
    float* denP         = (float*)(ws + 136314880);
    float* sPart        = (float*)(ws + 136839168);
    float* V            = (float*)(ws + 153616384);
    unsigned short* Vb2 = (unsigned short*)(ws + 153878528);

    xb_conv<<<512, 256, 0, stream>>>(x, xb);
    caps_conv0<<<1024, 256, 0, stream>>>(xb, W, Wb, sPart);   // conv + round 0
    caps_redsq<<<256, 64, 0, stream>>>((const float4*)sPart, V, Vb2, out, 0);
    for (int r = 1; r < 3; ++r) {
      caps_den<<<1024, 256, 0, stream>>>(xb, Wb, Vb2, denP);
      caps_accum<<<1024, 256, 0, stream>>>(xb, Wb, Vb2, denP, sPart);
      caps_redsq<<<256, 64, 0, stream>>>((const float4*)sPart, V, Vb2, out,
                                         r == 2 ? 2 : 1);
    }
  } else {
    float* s     = (float*)ws;
    float* V     = s + 65536;
    float* sPart = V + 65536;
    const size_t need1 = (2ull * 65536 + 512ull * 8192) * 4;
    const int usePart = (ws_size >= need1) ? 1 : 0;
    for (int r = 0; r < 3; ++r) {
      if (!usePart) fb_zero<<<256, 256, 0, stream>>>(s);
      fb_pass<<<512, 1024, 0, stream>>>(x, W, V, s, sPart, r, usePart);
      if (usePart)
        fb_reduceS<<<64, 256, 0, stream>>>((const float4*)sPart, (float4*)s);
      fb_squash<<<256, 256, 0, stream>>>(s, V, out, r == 2 ? 2 : (r == 0 ? 0 : 1));
    }
  }
}